// Round 8
// baseline (5778.062 us; speedup 1.0000x reference)
//
#include <hip/hip_runtime.h>
#include <hip/hip_bf16.h>
#include <cstring>

// ---- problem constants ----
#define NB 8
#define NT 64
#define NNODE 24
#define ND 6
#define NH 128
#define NR 64
#define NNE 4
#define NEDGE 552                  // NNODE*(NNODE-1)
#define NSEQ (NB*NEDGE)            // 4416
#define ROWS1 (NB*NNODE*NT)        // 12288
#define ROWS2 (NB*NEDGE*NT)        // 282624
#define PRIOR_SZ (NB*NT*NEDGE*NNE) // 1130496

typedef __hip_bfloat16 bf16;
typedef unsigned short u16;
typedef unsigned int u32;

__device__ __forceinline__ float eluf(float x){ return x > 0.f ? x : expm1f(x); }
__device__ __forceinline__ float b2f(bf16 v){ return __bfloat162float(v); }
__device__ __forceinline__ float bflo(u32 u){ return __uint_as_float(u << 16); }
__device__ __forceinline__ float bfhi(u32 u){ return __uint_as_float(u & 0xffff0000u); }
__device__ __forceinline__ u32 packbf2(float a, float b){
  bf16 ha = __float2bfloat16(a), hb = __float2bfloat16(b);
  u16 ua, ub;
  __builtin_memcpy(&ua, &ha, 2); __builtin_memcpy(&ub, &hb, 2);
  return (u32)ua | ((u32)ub << 16);
}

// ---------------- diagnostics / setup ----------------
__global__ void k_fill(float* out, int n, float pat){
  const int i = blockIdx.x*256 + threadIdx.x;
  if(i < n) out[i] = pat;
}
__global__ void k_zero(float* aux){
  for(int i = threadIdx.x; i < 1024; i += 256) aux[i] = 0.f;
}

// transpose GRU weights: wihT[k][row] = wih[row][k] (row in [0,192), k in [0,128))
//                        whhT[k][row] = whh[row][k] (k in [0,64))
__global__ void k_prep(const float* wihF, const float* whhF,
                       const float* wihR, const float* whhR,
                       float* wihTF, float* whhTF, float* wihTR, float* whhTR)
{
  const int i = blockIdx.x*256 + threadIdx.x;
  if(i < 192*128){
    const int r = i / NH, k = i - r*NH;
    wihTF[k*192 + r] = wihF[i];
    wihTR[k*192 + r] = wihR[i];
  }
  if(i < 192*64){
    const int r = i / NR, k = i - r*NR;
    whhTF[k*192 + r] = whhF[i];
    whhTR[k*192 + r] = whhR[i];
  }
}

// ---------------- MLP1: (B,N,T,D)->H->H, pre-BN out + channel sums -------------
__global__ __launch_bounds__(128) void k_mlp1(
    const float* inp, const float* w1, const float* b1,
    const float* w2, const float* b2,
    float* X1, float* sum, float* sq)
{
  const int j = threadIdx.x;
  __shared__ float xin[ND];
  __shared__ float h1[NH];
  const float b1j = b1[j], b2j = b2[j];
  float wcol[ND];
  for(int d = 0; d < ND; d++) wcol[d] = w1[d*NH + j];
  float accS = 0.f, accQ = 0.f;
  const int row0 = blockIdx.x*16;
  for(int r = 0; r < 16; r++){
    const int row = row0 + r;
    const int b = row/(NNODE*NT); const int rem = row - b*(NNODE*NT);
    const int n = rem/NT; const int t = rem - n*NT;
    if(j < ND) xin[j] = inp[((b*NT + t)*NNODE + n)*ND + j];
    __syncthreads();
    float a = b1j;
    for(int d = 0; d < ND; d++) a += xin[d]*wcol[d];
    h1[j] = eluf(a);
    __syncthreads();
    float a2 = b2j;
    for(int k = 0; k < NH; k++) a2 += h1[k]*w2[k*NH + j];
    const float h2 = eluf(a2);
    X1[row*NH + j] = h2; accS += h2; accQ += h2*h2;
    __syncthreads();
  }
  atomicAdd(&sum[j], accS); atomicAdd(&sq[j], accQ);
}

// ---------------- BN params ----------------
__global__ void k_bn(const float* sum, const float* sq,
                     const float* g, const float* be,
                     float inv_cnt, float* sc, float* sh)
{
  const int j = threadIdx.x;
  const float m = sum[j]*inv_cnt;
  const float v = fmaxf(sq[j]*inv_cnt - m*m, 0.f);
  const float s = g[j]*rsqrtf(v + 1e-5f);
  sc[j] = s; sh[j] = be[j] - m*s;
}

// ---------------- edge MLPs (MLP2: KIN=256, MLP4: KIN=384), CH=16 --------------
template<int KIN>
__global__ __launch_bounds__(128) void k_mlp_edge(
  const float* Xn, const float* scN, const float* shN,
  const bf16* Ein, const float* scE, const float* shE,
  const float* w1, const float* b1, const float* w2, const float* b2,
  bf16* Eo, float* sum, float* sq)
{
  const int j = threadIdx.x;
  constexpr int CH = 16, ST = 20;
  __shared__ __align__(16) float xin[KIN][ST];
  __shared__ __align__(16) float h1s[NH][ST];
  const int g0 = blockIdx.x*CH;
  const int b = g0/(NEDGE*NT); const int rem = g0 - b*(NEDGE*NT);
  const int e = rem/NT; const int t0 = rem - e*NT;
  const int snd = e/23, r0 = e - snd*23;
  const int rcv = r0 + (r0 >= snd ? 1 : 0);
  const float sN = scN[j], tN = shN[j];
  float sE = 0.f, tE = 0.f;
  if constexpr(KIN == 3*NH){ sE = scE[j]; tE = shE[j]; }
  const int baseS = ((b*NNODE + snd)*NT + t0)*NH;
  const int baseR = ((b*NNODE + rcv)*NT + t0)*NH;
  for(int r = 0; r < CH; r++){
    xin[j][r]      = Xn[baseS + r*NH + j]*sN + tN;
    xin[NH + j][r] = Xn[baseR + r*NH + j]*sN + tN;
    if constexpr(KIN == 3*NH)
      xin[2*NH + j][r] = b2f(Ein[(size_t)(g0 + r)*NH + j])*sE + tE;
  }
  __syncthreads();
  float acc[CH];
  const float b1j = b1[j];
  #pragma unroll
  for(int r = 0; r < CH; r++) acc[r] = b1j;
  for(int k = 0; k < KIN; k++){
    const float wv = w1[k*NH + j];
    const float4 xa = *(const float4*)&xin[k][0];
    const float4 xb = *(const float4*)&xin[k][4];
    const float4 xc = *(const float4*)&xin[k][8];
    const float4 xd = *(const float4*)&xin[k][12];
    acc[0]  += xa.x*wv; acc[1]  += xa.y*wv; acc[2]  += xa.z*wv; acc[3]  += xa.w*wv;
    acc[4]  += xb.x*wv; acc[5]  += xb.y*wv; acc[6]  += xb.z*wv; acc[7]  += xb.w*wv;
    acc[8]  += xc.x*wv; acc[9]  += xc.y*wv; acc[10] += xc.z*wv; acc[11] += xc.w*wv;
    acc[12] += xd.x*wv; acc[13] += xd.y*wv; acc[14] += xd.z*wv; acc[15] += xd.w*wv;
  }
  #pragma unroll
  for(int r = 0; r < CH; r++) h1s[j][r] = eluf(acc[r]);
  __syncthreads();
  const float b2j = b2[j];
  #pragma unroll
  for(int r = 0; r < CH; r++) acc[r] = b2j;
  for(int k = 0; k < NH; k++){
    const float wv = w2[k*NH + j];
    const float4 xa = *(const float4*)&h1s[k][0];
    const float4 xb = *(const float4*)&h1s[k][4];
    const float4 xc = *(const float4*)&h1s[k][8];
    const float4 xd = *(const float4*)&h1s[k][12];
    acc[0]  += xa.x*wv; acc[1]  += xa.y*wv; acc[2]  += xa.z*wv; acc[3]  += xa.w*wv;
    acc[4]  += xb.x*wv; acc[5]  += xb.y*wv; acc[6]  += xb.z*wv; acc[7]  += xb.w*wv;
    acc[8]  += xc.x*wv; acc[9]  += xc.y*wv; acc[10] += xc.z*wv; acc[11] += xc.w*wv;
    acc[12] += xd.x*wv; acc[13] += xd.y*wv; acc[14] += xd.z*wv; acc[15] += xd.w*wv;
  }
  float accS = 0.f, accQ = 0.f;
  #pragma unroll
  for(int r = 0; r < CH; r++){
    const float h2 = eluf(acc[r]);
    Eo[(size_t)(g0 + r)*NH + j] = __float2bfloat16(h2);
    accS += h2; accQ += h2*h2;
  }
  atomicAdd(&sum[j], accS); atomicAdd(&sq[j], accQ);
}

// ---------------- agg (mean over incoming edges) + MLP3 ----------------
__global__ __launch_bounds__(128) void k_mlp3(
    const bf16* Ein, const float* scE, const float* shE,
    const float* w1, const float* b1, const float* w2, const float* b2,
    float* X3, float* sum, float* sq)
{
  const int j = threadIdx.x;
  __shared__ float xin[NH];
  __shared__ float h1[NH];
  const float sE = scE[j], tE = shE[j];
  float accS = 0.f, accQ = 0.f;
  const int row0 = blockIdx.x*16;
  for(int r = 0; r < 16; r++){
    const int row = row0 + r;
    const int b = row/(NNODE*NT); const int rem = row - b*(NNODE*NT);
    const int n = rem/NT; const int t = rem - n*NT;
    float s = 0.f;
    for(int i = 0; i < NNODE; i++){
      if(i == n) continue;
      const int e = i*23 + (n < i ? n : n - 1);
      s += b2f(Ein[((size_t)(b*NEDGE + e)*NT + t)*NH + j]);
    }
    xin[j] = sE*s*(1.f/23.f) + tE;
    __syncthreads();
    float a = b1[j];
    for(int k = 0; k < NH; k++) a += xin[k]*w1[k*NH + j];
    h1[j] = eluf(a);
    __syncthreads();
    float a2 = b2[j];
    for(int k = 0; k < NH; k++) a2 += h1[k]*w2[k*NH + j];
    const float h2 = eluf(a2);
    X3[row*NH + j] = h2; accS += h2; accQ += h2*h2;
    __syncthreads();
  }
  atomicAdd(&sum[j], accS); atomicAdd(&sq[j], accQ);
}

// ---------------- GRU: one wave per (sequence,direction) ----------------------
// Phase 1: xw for all 64 steps kept in REGISTERS (packed bf16x2, proc-order).
// Phase 2: fully-unrolled recurrence, h fp32 in LDS, whhT packed bf16 in regs,
//          h_t history stored bf16 to LDS.
// Epilogue: projections (prior/enc) computed per-timestep-lane from history.
__global__ __launch_bounds__(64, 2) void k_gru(
  const bf16* E4, const float* sc4, const float* sh4,
  const float* wihTF, const float* whhTF, const float* bihF, const float* bhhF,
  const float* wihTR, const float* whhTR, const float* bihR, const float* bhhR,
  const float* pw, const float* pb, const float* ew,
  bf16* encpF, bf16* encpR, float* outP, float* hT)
{
  __shared__ __align__(16) float xst[NH][20];     // 10240 B
  __shared__ __align__(16) bf16 hist[NT][66];     // 8448 B
  __shared__ __align__(16) float hs[NR];          // 256 B
  const int c = threadIdx.x;
  const int bid = blockIdx.x;
  const int dir = (bid >= NSEQ) ? 1 : 0;
  const int s = dir ? (bid - NSEQ) : bid;
  const int sb = s / NEDGE, se = s - sb*NEDGE;
  const float* wihT = dir ? wihTR : wihTF;
  const float* whhT = dir ? whhTR : whhTF;
  const float* bih  = dir ? bihR  : bihF;
  const float* bhh  = dir ? bhhR  : bhhF;
  const float bxr = bih[c], bxz = bih[64+c], bxn = bih[128+c];
  const float bhr = bhh[c], bhz = bhh[64+c], bhn = bhh[128+c];
  const float sc_a = sc4[c], sc_b = sc4[c+64];
  const float sh_a = sh4[c], sh_b = sh4[c+64];

  u32 xwr[32], xwz[32], xwn[32];   // xw in proc order, packed (even,odd) steps

  // ---- phase 1: x-projection into registers ----
  #pragma unroll
  for(int T = 0; T < 4; T++){
    for(int tp = 0; tp < 16; tp++){
      const int p = T*16 + tp;
      const int t = dir ? (NT - 1 - p) : p;
      const size_t xb = ((size_t)s*NT + t)*NH;
      xst[c][tp]      = b2f(E4[xb + c])*sc_a + sh_a;
      xst[c + 64][tp] = b2f(E4[xb + c + 64])*sc_b + sh_b;
    }
    __syncthreads();
    float ar[16], az[16], an[16];
    #pragma unroll
    for(int tp = 0; tp < 16; tp++){ ar[tp] = bxr; az[tp] = bxz; an[tp] = bxn; }
    for(int k = 0; k < NH; k++){
      const float wr = wihT[k*192 + c];
      const float wz = wihT[k*192 + 64 + c];
      const float wn = wihT[k*192 + 128 + c];
      const float4 x0 = *(const float4*)&xst[k][0];
      const float4 x1 = *(const float4*)&xst[k][4];
      const float4 x2 = *(const float4*)&xst[k][8];
      const float4 x3 = *(const float4*)&xst[k][12];
      float xv[16] = {x0.x,x0.y,x0.z,x0.w, x1.x,x1.y,x1.z,x1.w,
                      x2.x,x2.y,x2.z,x2.w, x3.x,x3.y,x3.z,x3.w};
      #pragma unroll
      for(int tp = 0; tp < 16; tp++){
        ar[tp] += xv[tp]*wr; az[tp] += xv[tp]*wz; an[tp] += xv[tp]*wn;
      }
    }
    #pragma unroll
    for(int tp = 0; tp < 16; tp += 2){
      xwr[T*8 + tp/2] = packbf2(ar[tp], ar[tp+1]);
      xwz[T*8 + tp/2] = packbf2(az[tp], az[tp+1]);
      xwn[T*8 + tp/2] = packbf2(an[tp], an[tp+1]);
    }
    __syncthreads();
  }

  // ---- whhT into registers (packed bf16x2) ----
  u32 wr2[32], wz2[32], wn2[32];
  #pragma unroll
  for(int kk = 0; kk < 32; kk++){
    wr2[kk] = packbf2(whhT[(2*kk)*192 + c],        whhT[(2*kk+1)*192 + c]);
    wz2[kk] = packbf2(whhT[(2*kk)*192 + 64 + c],   whhT[(2*kk+1)*192 + 64 + c]);
    wn2[kk] = packbf2(whhT[(2*kk)*192 + 128 + c],  whhT[(2*kk+1)*192 + 128 + c]);
  }

  // ---- phase 2: recurrence (fully unrolled for constant xw indices) ----
  hs[c] = 0.f;
  float hprev = 0.f;
  __syncthreads();
  #pragma unroll
  for(int p = 0; p < NT; p++){
    const u32 pr_ = xwr[p/2], pz_ = xwz[p/2], pn_ = xwn[p/2];
    const float xr = (p & 1) ? bfhi(pr_) : bflo(pr_);
    const float xz = (p & 1) ? bfhi(pz_) : bflo(pz_);
    const float xn = (p & 1) ? bfhi(pn_) : bflo(pn_);
    float hr = bhr, hz = bhz, hn = bhn;
    #pragma unroll
    for(int kk = 0; kk < 32; kk++){
      const float2 hp = *(const float2*)&hs[2*kk];
      const u32 ur = wr2[kk], uz = wz2[kk], un = wn2[kk];
      hr += hp.x*bflo(ur) + hp.y*bfhi(ur);
      hz += hp.x*bflo(uz) + hp.y*bfhi(uz);
      hn += hp.x*bflo(un) + hp.y*bfhi(un);
    }
    const float rg = 1.f/(1.f + expf(-(xr + hr)));
    const float zg = 1.f/(1.f + expf(-(xz + hz)));
    const float ng = tanhf(xn + rg*hn);
    const float hnew = (1.f - zg)*ng + zg*hprev;
    __syncthreads();
    hs[c] = hnew; hprev = hnew;
    hist[p][c] = __float2bfloat16(hnew);
    __syncthreads();
  }
  if(!dir) hT[(size_t)s*NR + c] = hprev;

  // ---- epilogue: projections; lane c owns proc step p = c ----
  const int t = dir ? (NT - 1 - c) : c;
  if(!dir){
    float ap[NNE] = {pb[0], pb[1], pb[2], pb[3]};
    float ae[NNE] = {0.f, 0.f, 0.f, 0.f};
    for(int kk = 0; kk < 32; kk++){
      u32 hp; __builtin_memcpy(&hp, &hist[c][2*kk], 4);
      const float h0 = bflo(hp), h1 = bfhi(hp);
      #pragma unroll
      for(int l = 0; l < NNE; l++){
        ap[l] += h0*pw[(2*kk)*NNE + l] + h1*pw[(2*kk+1)*NNE + l];
        ae[l] += h0*ew[(2*kk)*NNE + l] + h1*ew[(2*kk+1)*NNE + l];
      }
    }
    float4 pv = {ap[0], ap[1], ap[2], ap[3]};
    *(float4*)&outP[(((size_t)(sb*NT + t))*NEDGE + se)*NNE] = pv;
    u32 e01 = packbf2(ae[0], ae[1]), e23 = packbf2(ae[2], ae[3]);
    u32* ed = (u32*)&encpF[((size_t)s*NT + t)*NNE];
    ed[0] = e01; ed[1] = e23;
  } else {
    float ae[NNE] = {0.f, 0.f, 0.f, 0.f};
    for(int kk = 0; kk < 32; kk++){
      u32 hp; __builtin_memcpy(&hp, &hist[c][2*kk], 4);
      const float h0 = bflo(hp), h1 = bfhi(hp);
      #pragma unroll
      for(int l = 0; l < NNE; l++){
        ae[l] += h0*ew[(NR + 2*kk)*NNE + l] + h1*ew[(NR + 2*kk+1)*NNE + l];
      }
    }
    u32 e01 = packbf2(ae[0], ae[1]), e23 = packbf2(ae[2], ae[3]);
    u32* ed = (u32*)&encpR[((size_t)s*NT + t)*NNE];
    ed[0] = e01; ed[1] = e23;
  }
}

// ---------------- merge enc halves + bias ----------------
__global__ void k_add(const bf16* eF, const bf16* eR, const float* eb, float* outE){
  const int i = blockIdx.x*256 + threadIdx.x;
  if(i >= PRIOR_SZ) return;
  const int l = i & 3; const int r2 = i >> 2;
  const int e = r2 % NEDGE; const int r3 = r2 / NEDGE;
  const int t = r3 % NT; const int b = r3 / NT;
  const int s = b*NEDGE + e;
  const size_t src = ((size_t)s*NT + t)*NNE + l;
  outE[i] = b2f(eF[src]) + b2f(eR[src]) + eb[l];
}

extern "C" void kernel_launch(void* const* d_in, const int* in_sizes, int n_in,
                              void* d_out, int out_size, void* d_ws, size_t ws_size,
                              hipStream_t stream)
{
  const size_t NEED = 78659584ull;
  if(ws_size < NEED){
    k_fill<<<(out_size + 255)/256, 256, 0, stream>>>((float*)d_out, out_size, 3584.0f);
    return;
  }
  const float* inp  = (const float*)d_in[0];
  const float* m1w1 = (const float*)d_in[1];  const float* m1b1 = (const float*)d_in[2];
  const float* m1w2 = (const float*)d_in[3];  const float* m1b2 = (const float*)d_in[4];
  const float* m1g  = (const float*)d_in[5];  const float* m1be = (const float*)d_in[6];
  const float* m2w1 = (const float*)d_in[7];  const float* m2b1 = (const float*)d_in[8];
  const float* m2w2 = (const float*)d_in[9];  const float* m2b2 = (const float*)d_in[10];
  const float* m2g  = (const float*)d_in[11]; const float* m2be = (const float*)d_in[12];
  const float* m3w1 = (const float*)d_in[13]; const float* m3b1 = (const float*)d_in[14];
  const float* m3w2 = (const float*)d_in[15]; const float* m3b2 = (const float*)d_in[16];
  const float* m3g  = (const float*)d_in[17]; const float* m3be = (const float*)d_in[18];
  const float* m4w1 = (const float*)d_in[19]; const float* m4b1 = (const float*)d_in[20];
  const float* m4w2 = (const float*)d_in[21]; const float* m4b2 = (const float*)d_in[22];
  const float* m4g  = (const float*)d_in[23]; const float* m4be = (const float*)d_in[24];
  const float* wihF = (const float*)d_in[25]; const float* whhF = (const float*)d_in[26];
  const float* bihF = (const float*)d_in[27]; const float* bhhF = (const float*)d_in[28];
  const float* wihR = (const float*)d_in[29]; const float* whhR = (const float*)d_in[30];
  const float* bihR = (const float*)d_in[31]; const float* bhhR = (const float*)d_in[32];
  const float* pw   = (const float*)d_in[33]; const float* pb   = (const float*)d_in[34];
  const float* ew   = (const float*)d_in[35]; const float* eb   = (const float*)d_in[36];

  char* ws = (char*)d_ws;
  float* AUX = (float*)(ws + 0);             // 16 KB reserved
  char*  Xr  = ws + 16384;                   // 6,291,456 B (X1 then X3)
  float* X   = (float*)Xr;
  bf16*  E   = (bf16*)(ws + 16384 + 6291456); // 72,351,744 B (E2 then in-place E4)
  // aliases inside X region, valid AFTER mlp4 has consumed X3:
  float* wihTF = (float*)(Xr + 0);           // 98,304 B
  float* wihTR = (float*)(Xr + 98304);       // 98,304 B
  float* whhTF = (float*)(Xr + 196608);      // 49,152 B
  float* whhTR = (float*)(Xr + 245760);      // 49,152 B -> 294,912
  bf16*  encpF = (bf16*)(Xr + 294912);       // 2,260,992 B
  bf16*  encpR = (bf16*)(Xr + 2555904);      // 2,260,992 B -> 4,816,896 <= 6,291,456

  float* SUM0 = AUX + 0*128;        float* SUM1 = AUX + 1*128;
  float* SUM2 = AUX + 2*128;        float* SUM3 = AUX + 3*128;
  float* SQ0  = AUX + 512 + 0*128;  float* SQ1  = AUX + 512 + 1*128;
  float* SQ2  = AUX + 512 + 2*128;  float* SQ3  = AUX + 512 + 3*128;
  float* SC0  = AUX + 1024 + 0*128; float* SC1  = AUX + 1024 + 1*128;
  float* SC2  = AUX + 1024 + 2*128; float* SC3  = AUX + 1024 + 3*128;
  float* SH0  = AUX + 1536 + 0*128; float* SH1  = AUX + 1536 + 1*128;
  float* SH2  = AUX + 1536 + 2*128; float* SH3  = AUX + 1536 + 3*128;

  float* outP = (float*)d_out;
  float* outE = outP + PRIOR_SZ;
  float* hT   = outP + 2*PRIOR_SZ;

  k_zero<<<1, 256, 0, stream>>>(AUX);
  k_mlp1<<<ROWS1/16, 128, 0, stream>>>(inp, m1w1, m1b1, m1w2, m1b2, X, SUM0, SQ0);
  k_bn<<<1, 128, 0, stream>>>(SUM0, SQ0, m1g, m1be, 1.f/ROWS1, SC0, SH0);
  k_mlp_edge<2*NH><<<ROWS2/16, 128, 0, stream>>>(X, SC0, SH0, nullptr, nullptr, nullptr,
                                                 m2w1, m2b1, m2w2, m2b2, E, SUM1, SQ1);
  k_bn<<<1, 128, 0, stream>>>(SUM1, SQ1, m2g, m2be, 1.f/ROWS2, SC1, SH1);
  k_mlp3<<<ROWS1/16, 128, 0, stream>>>(E, SC1, SH1, m3w1, m3b1, m3w2, m3b2, X, SUM2, SQ2);
  k_bn<<<1, 128, 0, stream>>>(SUM2, SQ2, m3g, m3be, 1.f/ROWS1, SC2, SH2);
  k_mlp_edge<3*NH><<<ROWS2/16, 128, 0, stream>>>(X, SC2, SH2, E, SC1, SH1,
                                                 m4w1, m4b1, m4w2, m4b2, E, SUM3, SQ3);
  k_bn<<<1, 128, 0, stream>>>(SUM3, SQ3, m4g, m4be, 1.f/ROWS2, SC3, SH3);
  // X region is now dead -> transpose GRU weights into it
  k_prep<<<96, 256, 0, stream>>>(wihF, whhF, wihR, whhR, wihTF, whhTF, wihTR, whhTR);
  k_gru<<<2*NSEQ, 64, 0, stream>>>(E, SC3, SH3,
                                   wihTF, whhTF, bihF, bhhF,
                                   wihTR, whhTR, bihR, bhhR,
                                   pw, pb, ew, encpF, encpR, outP, hT);
  k_add<<<(PRIOR_SZ + 255)/256, 256, 0, stream>>>(encpF, encpR, eb, outE);
}

// Round 9
// 2980.466 us; speedup vs baseline: 1.9386x; 1.9386x over previous
//
#include <hip/hip_runtime.h>
#include <hip/hip_bf16.h>
#include <cstring>

// ---- problem constants ----
#define NB 8
#define NT 64
#define NNODE 24
#define ND 6
#define NH 128
#define NR 64
#define NNE 4
#define NEDGE 552                  // NNODE*(NNODE-1)
#define NSEQ (NB*NEDGE)            // 4416
#define ROWS1 (NB*NNODE*NT)        // 12288
#define ROWS2 (NB*NEDGE*NT)        // 282624
#define PRIOR_SZ (NB*NT*NEDGE*NNE) // 1130496

typedef __hip_bfloat16 bf16;
typedef unsigned short u16;
typedef unsigned int u32;

__device__ __forceinline__ float eluf(float x){ return x > 0.f ? x : expm1f(x); }
__device__ __forceinline__ float b2f(bf16 v){ return __bfloat162float(v); }
__device__ __forceinline__ float bflo(u32 u){ return __uint_as_float(u << 16); }
__device__ __forceinline__ float bfhi(u32 u){ return __uint_as_float(u & 0xffff0000u); }
__device__ __forceinline__ u32 packbf2(float a, float b){
  bf16 ha = __float2bfloat16(a), hb = __float2bfloat16(b);
  u16 ua, ub;
  __builtin_memcpy(&ua, &ha, 2); __builtin_memcpy(&ub, &hb, 2);
  return (u32)ua | ((u32)ub << 16);
}

// ---------------- diagnostics / setup ----------------
__global__ void k_fill(float* out, int n, float pat){
  const int i = blockIdx.x*256 + threadIdx.x;
  if(i < n) out[i] = pat;
}
__global__ void k_zero(float* aux){
  for(int i = threadIdx.x; i < 1024; i += 256) aux[i] = 0.f;
}

// transpose GRU weights: wihT[k][row] = wih[row][k] (row in [0,192), k in [0,128))
//                        whhT[k][row] = whh[row][k] (k in [0,64))
__global__ void k_prep(const float* wihF, const float* whhF,
                       const float* wihR, const float* whhR,
                       float* wihTF, float* whhTF, float* wihTR, float* whhTR)
{
  const int i = blockIdx.x*256 + threadIdx.x;
  if(i < 192*128){
    const int r = i / NH, k = i - r*NH;
    wihTF[k*192 + r] = wihF[i];
    wihTR[k*192 + r] = wihR[i];
  }
  if(i < 192*64){
    const int r = i / NR, k = i - r*NR;
    whhTF[k*192 + r] = whhF[i];
    whhTR[k*192 + r] = whhR[i];
  }
}

// ---------------- MLP1: (B,N,T,D)->H->H, pre-BN out + channel sums -------------
__global__ __launch_bounds__(128) void k_mlp1(
    const float* inp, const float* w1, const float* b1,
    const float* w2, const float* b2,
    float* X1, float* sum, float* sq)
{
  const int j = threadIdx.x;
  __shared__ float xin[ND];
  __shared__ float h1[NH];
  const float b1j = b1[j], b2j = b2[j];
  float wcol[ND];
  for(int d = 0; d < ND; d++) wcol[d] = w1[d*NH + j];
  float accS = 0.f, accQ = 0.f;
  const int row0 = blockIdx.x*16;
  for(int r = 0; r < 16; r++){
    const int row = row0 + r;
    const int b = row/(NNODE*NT); const int rem = row - b*(NNODE*NT);
    const int n = rem/NT; const int t = rem - n*NT;
    if(j < ND) xin[j] = inp[((b*NT + t)*NNODE + n)*ND + j];
    __syncthreads();
    float a = b1j;
    for(int d = 0; d < ND; d++) a += xin[d]*wcol[d];
    h1[j] = eluf(a);
    __syncthreads();
    float a2 = b2j;
    for(int k = 0; k < NH; k++) a2 += h1[k]*w2[k*NH + j];
    const float h2 = eluf(a2);
    X1[row*NH + j] = h2; accS += h2; accQ += h2*h2;
    __syncthreads();
  }
  atomicAdd(&sum[j], accS); atomicAdd(&sq[j], accQ);
}

// ---------------- BN params ----------------
__global__ void k_bn(const float* sum, const float* sq,
                     const float* g, const float* be,
                     float inv_cnt, float* sc, float* sh)
{
  const int j = threadIdx.x;
  const float m = sum[j]*inv_cnt;
  const float v = fmaxf(sq[j]*inv_cnt - m*m, 0.f);
  const float s = g[j]*rsqrtf(v + 1e-5f);
  sc[j] = s; sh[j] = be[j] - m*s;
}

// ---------------- edge MLPs (MLP2: KIN=256, MLP4: KIN=384), CH=16 --------------
template<int KIN>
__global__ __launch_bounds__(128) void k_mlp_edge(
  const float* Xn, const float* scN, const float* shN,
  const bf16* Ein, const float* scE, const float* shE,
  const float* w1, const float* b1, const float* w2, const float* b2,
  bf16* Eo, float* sum, float* sq)
{
  const int j = threadIdx.x;
  constexpr int CH = 16, ST = 20;
  __shared__ __align__(16) float xin[KIN][ST];
  __shared__ __align__(16) float h1s[NH][ST];
  const int g0 = blockIdx.x*CH;
  const int b = g0/(NEDGE*NT); const int rem = g0 - b*(NEDGE*NT);
  const int e = rem/NT; const int t0 = rem - e*NT;
  const int snd = e/23, r0 = e - snd*23;
  const int rcv = r0 + (r0 >= snd ? 1 : 0);
  const float sN = scN[j], tN = shN[j];
  float sE = 0.f, tE = 0.f;
  if constexpr(KIN == 3*NH){ sE = scE[j]; tE = shE[j]; }
  const int baseS = ((b*NNODE + snd)*NT + t0)*NH;
  const int baseR = ((b*NNODE + rcv)*NT + t0)*NH;
  for(int r = 0; r < CH; r++){
    xin[j][r]      = Xn[baseS + r*NH + j]*sN + tN;
    xin[NH + j][r] = Xn[baseR + r*NH + j]*sN + tN;
    if constexpr(KIN == 3*NH)
      xin[2*NH + j][r] = b2f(Ein[(size_t)(g0 + r)*NH + j])*sE + tE;
  }
  __syncthreads();
  float acc[CH];
  const float b1j = b1[j];
  #pragma unroll
  for(int r = 0; r < CH; r++) acc[r] = b1j;
  for(int k = 0; k < KIN; k++){
    const float wv = w1[k*NH + j];
    const float4 xa = *(const float4*)&xin[k][0];
    const float4 xb = *(const float4*)&xin[k][4];
    const float4 xc = *(const float4*)&xin[k][8];
    const float4 xd = *(const float4*)&xin[k][12];
    acc[0]  += xa.x*wv; acc[1]  += xa.y*wv; acc[2]  += xa.z*wv; acc[3]  += xa.w*wv;
    acc[4]  += xb.x*wv; acc[5]  += xb.y*wv; acc[6]  += xb.z*wv; acc[7]  += xb.w*wv;
    acc[8]  += xc.x*wv; acc[9]  += xc.y*wv; acc[10] += xc.z*wv; acc[11] += xc.w*wv;
    acc[12] += xd.x*wv; acc[13] += xd.y*wv; acc[14] += xd.z*wv; acc[15] += xd.w*wv;
  }
  #pragma unroll
  for(int r = 0; r < CH; r++) h1s[j][r] = eluf(acc[r]);
  __syncthreads();
  const float b2j = b2[j];
  #pragma unroll
  for(int r = 0; r < CH; r++) acc[r] = b2j;
  for(int k = 0; k < NH; k++){
    const float wv = w2[k*NH + j];
    const float4 xa = *(const float4*)&h1s[k][0];
    const float4 xb = *(const float4*)&h1s[k][4];
    const float4 xc = *(const float4*)&h1s[k][8];
    const float4 xd = *(const float4*)&h1s[k][12];
    acc[0]  += xa.x*wv; acc[1]  += xa.y*wv; acc[2]  += xa.z*wv; acc[3]  += xa.w*wv;
    acc[4]  += xb.x*wv; acc[5]  += xb.y*wv; acc[6]  += xb.z*wv; acc[7]  += xb.w*wv;
    acc[8]  += xc.x*wv; acc[9]  += xc.y*wv; acc[10] += xc.z*wv; acc[11] += xc.w*wv;
    acc[12] += xd.x*wv; acc[13] += xd.y*wv; acc[14] += xd.z*wv; acc[15] += xd.w*wv;
  }
  float accS = 0.f, accQ = 0.f;
  #pragma unroll
  for(int r = 0; r < CH; r++){
    const float h2 = eluf(acc[r]);
    Eo[(size_t)(g0 + r)*NH + j] = __float2bfloat16(h2);
    accS += h2; accQ += h2*h2;
  }
  atomicAdd(&sum[j], accS); atomicAdd(&sq[j], accQ);
}

// ---------------- agg (mean over incoming edges) + MLP3 ----------------
__global__ __launch_bounds__(128) void k_mlp3(
    const bf16* Ein, const float* scE, const float* shE,
    const float* w1, const float* b1, const float* w2, const float* b2,
    float* X3, float* sum, float* sq)
{
  const int j = threadIdx.x;
  __shared__ float xin[NH];
  __shared__ float h1[NH];
  const float sE = scE[j], tE = shE[j];
  float accS = 0.f, accQ = 0.f;
  const int row0 = blockIdx.x*16;
  for(int r = 0; r < 16; r++){
    const int row = row0 + r;
    const int b = row/(NNODE*NT); const int rem = row - b*(NNODE*NT);
    const int n = rem/NT; const int t = rem - n*NT;
    float s = 0.f;
    for(int i = 0; i < NNODE; i++){
      if(i == n) continue;
      const int e = i*23 + (n < i ? n : n - 1);
      s += b2f(Ein[((size_t)(b*NEDGE + e)*NT + t)*NH + j]);
    }
    xin[j] = sE*s*(1.f/23.f) + tE;
    __syncthreads();
    float a = b1[j];
    for(int k = 0; k < NH; k++) a += xin[k]*w1[k*NH + j];
    h1[j] = eluf(a);
    __syncthreads();
    float a2 = b2[j];
    for(int k = 0; k < NH; k++) a2 += h1[k]*w2[k*NH + j];
    const float h2 = eluf(a2);
    X3[row*NH + j] = h2; accS += h2; accQ += h2*h2;
    __syncthreads();
  }
  atomicAdd(&sum[j], accS); atomicAdd(&sq[j], accQ);
}

// ---------------- GRU: one wave per (sequence,direction), chunked -------------
// 4 chunks of 16 steps: stage x (bf16 LDS) -> xw GEMM chunk into LDS -> 16
// recurrence steps. whhT packed bf16 in registers; h fp32 in LDS; h history
// bf16 in LDS. Epilogue: lane p projects timestep p (no per-step butterfly).
// LDS: 4096(xst)+6144(xwb)+8448(hist)+256(hs) = 18,944 B -> 8 blocks/CU.
__global__ __launch_bounds__(64) void k_gru(
  const bf16* E4, const float* sc4, const float* sh4,
  const float* wihTF, const float* whhTF, const float* bihF, const float* bhhF,
  const float* wihTR, const float* whhTR, const float* bihR, const float* bhhR,
  const float* pw, const float* pb, const float* ew,
  bf16* encpF, bf16* encpR, float* outP, float* hT)
{
  __shared__ __align__(16) bf16 xst[NH][16];      // 4096 B
  __shared__ __align__(16) bf16 xwb[16][192];     // 6144 B
  __shared__ __align__(16) bf16 hist[NT][66];     // 8448 B
  __shared__ __align__(16) float hs[NR];          // 256 B
  const int c = threadIdx.x;
  const int bid = blockIdx.x;
  const int dir = (bid >= NSEQ) ? 1 : 0;
  const int s = dir ? (bid - NSEQ) : bid;
  const int sb = s / NEDGE, se = s - sb*NEDGE;
  const float* wihT = dir ? wihTR : wihTF;
  const float* whhT = dir ? whhTR : whhTF;
  const float* bih  = dir ? bihR  : bihF;
  const float* bhh  = dir ? bhhR  : bhhF;
  const float bxr = bih[c], bxz = bih[64+c], bxn = bih[128+c];
  const float bhr = bhh[c], bhz = bhh[64+c], bhn = bhh[128+c];
  const float sc_a = sc4[c], sc_b = sc4[c+64];
  const float sh_a = sh4[c], sh_b = sh4[c+64];

  // whhT into registers (packed bf16x2) — ~96 VGPRs, no spill at 64 thr/wave
  u32 wr2[32], wz2[32], wn2[32];
  #pragma unroll
  for(int kk = 0; kk < 32; kk++){
    wr2[kk] = packbf2(whhT[(2*kk)*192 + c],        whhT[(2*kk+1)*192 + c]);
    wz2[kk] = packbf2(whhT[(2*kk)*192 + 64 + c],   whhT[(2*kk+1)*192 + 64 + c]);
    wn2[kk] = packbf2(whhT[(2*kk)*192 + 128 + c],  whhT[(2*kk+1)*192 + 128 + c]);
  }

  hs[c] = 0.f;
  float hprev = 0.f;
  __syncthreads();

  for(int T = 0; T < 4; T++){
    // ---- stage 16 timesteps of x (proc order) ----
    for(int tp = 0; tp < 16; tp++){
      const int p = T*16 + tp;
      const int t = dir ? (NT - 1 - p) : p;
      const size_t xb = ((size_t)s*NT + t)*NH;
      xst[c][tp]      = __float2bfloat16(b2f(E4[xb + c])*sc_a + sh_a);
      xst[c + 64][tp] = __float2bfloat16(b2f(E4[xb + c + 64])*sc_b + sh_b);
    }
    __syncthreads();
    // ---- xw GEMM chunk: 16 steps x 3 gates for this lane's channel ----
    float ar[16], az[16], an[16];
    #pragma unroll
    for(int tp = 0; tp < 16; tp++){ ar[tp] = bxr; az[tp] = bxz; an[tp] = bxn; }
    for(int k = 0; k < NH; k++){
      const float wr = wihT[k*192 + c];
      const float wz = wihT[k*192 + 64 + c];
      const float wn = wihT[k*192 + 128 + c];
      const uint4 q0 = *(const uint4*)&xst[k][0];
      const uint4 q1 = *(const uint4*)&xst[k][8];
      float xv[16];
      xv[0]=bflo(q0.x); xv[1]=bfhi(q0.x); xv[2]=bflo(q0.y); xv[3]=bfhi(q0.y);
      xv[4]=bflo(q0.z); xv[5]=bfhi(q0.z); xv[6]=bflo(q0.w); xv[7]=bfhi(q0.w);
      xv[8]=bflo(q1.x); xv[9]=bfhi(q1.x); xv[10]=bflo(q1.y); xv[11]=bfhi(q1.y);
      xv[12]=bflo(q1.z); xv[13]=bfhi(q1.z); xv[14]=bflo(q1.w); xv[15]=bfhi(q1.w);
      #pragma unroll
      for(int tp = 0; tp < 16; tp++){
        ar[tp] += xv[tp]*wr; az[tp] += xv[tp]*wz; an[tp] += xv[tp]*wn;
      }
    }
    #pragma unroll
    for(int tp = 0; tp < 16; tp++){
      xwb[tp][c]       = __float2bfloat16(ar[tp]);
      xwb[tp][64 + c]  = __float2bfloat16(az[tp]);
      xwb[tp][128 + c] = __float2bfloat16(an[tp]);
    }
    __syncthreads();
    // ---- 16 recurrence steps ----
    for(int pp = 0; pp < 16; pp++){
      const float xr = b2f(xwb[pp][c]);
      const float xz = b2f(xwb[pp][64 + c]);
      const float xn = b2f(xwb[pp][128 + c]);
      float hr = bhr, hz = bhz, hn = bhn;
      #pragma unroll
      for(int kk = 0; kk < 32; kk++){
        const float2 hp = *(const float2*)&hs[2*kk];
        const u32 ur = wr2[kk], uz = wz2[kk], un = wn2[kk];
        hr += hp.x*bflo(ur) + hp.y*bfhi(ur);
        hz += hp.x*bflo(uz) + hp.y*bfhi(uz);
        hn += hp.x*bflo(un) + hp.y*bfhi(un);
      }
      const float rg = 1.f/(1.f + expf(-(xr + hr)));
      const float zg = 1.f/(1.f + expf(-(xz + hz)));
      const float ng = tanhf(xn + rg*hn);
      const float hnew = (1.f - zg)*ng + zg*hprev;
      __syncthreads();
      hs[c] = hnew; hprev = hnew;
      hist[T*16 + pp][c] = __float2bfloat16(hnew);
      __syncthreads();
    }
  }
  if(!dir) hT[(size_t)s*NR + c] = hprev;

  // ---- epilogue: projections; lane c owns proc step p = c ----
  const int t = dir ? (NT - 1 - c) : c;
  if(!dir){
    float ap[NNE] = {pb[0], pb[1], pb[2], pb[3]};
    float ae[NNE] = {0.f, 0.f, 0.f, 0.f};
    for(int kk = 0; kk < 32; kk++){
      u32 hp; __builtin_memcpy(&hp, &hist[c][2*kk], 4);
      const float h0 = bflo(hp), h1 = bfhi(hp);
      #pragma unroll
      for(int l = 0; l < NNE; l++){
        ap[l] += h0*pw[(2*kk)*NNE + l] + h1*pw[(2*kk+1)*NNE + l];
        ae[l] += h0*ew[(2*kk)*NNE + l] + h1*ew[(2*kk+1)*NNE + l];
      }
    }
    float4 pv = {ap[0], ap[1], ap[2], ap[3]};
    *(float4*)&outP[(((size_t)(sb*NT + t))*NEDGE + se)*NNE] = pv;
    u32 e01 = packbf2(ae[0], ae[1]), e23 = packbf2(ae[2], ae[3]);
    u32* ed = (u32*)&encpF[((size_t)s*NT + t)*NNE];
    ed[0] = e01; ed[1] = e23;
  } else {
    float ae[NNE] = {0.f, 0.f, 0.f, 0.f};
    for(int kk = 0; kk < 32; kk++){
      u32 hp; __builtin_memcpy(&hp, &hist[c][2*kk], 4);
      const float h0 = bflo(hp), h1 = bfhi(hp);
      #pragma unroll
      for(int l = 0; l < NNE; l++){
        ae[l] += h0*ew[(NR + 2*kk)*NNE + l] + h1*ew[(NR + 2*kk+1)*NNE + l];
      }
    }
    u32 e01 = packbf2(ae[0], ae[1]), e23 = packbf2(ae[2], ae[3]);
    u32* ed = (u32*)&encpR[((size_t)s*NT + t)*NNE];
    ed[0] = e01; ed[1] = e23;
  }
}

// ---------------- merge enc halves + bias ----------------
__global__ void k_add(const bf16* eF, const bf16* eR, const float* eb, float* outE){
  const int i = blockIdx.x*256 + threadIdx.x;
  if(i >= PRIOR_SZ) return;
  const int l = i & 3; const int r2 = i >> 2;
  const int e = r2 % NEDGE; const int r3 = r2 / NEDGE;
  const int t = r3 % NT; const int b = r3 / NT;
  const int s = b*NEDGE + e;
  const size_t src = ((size_t)s*NT + t)*NNE + l;
  outE[i] = b2f(eF[src]) + b2f(eR[src]) + eb[l];
}

extern "C" void kernel_launch(void* const* d_in, const int* in_sizes, int n_in,
                              void* d_out, int out_size, void* d_ws, size_t ws_size,
                              hipStream_t stream)
{
  const size_t NEED = 78659584ull;
  if(ws_size < NEED){
    k_fill<<<(out_size + 255)/256, 256, 0, stream>>>((float*)d_out, out_size, 3584.0f);
    return;
  }
  const float* inp  = (const float*)d_in[0];
  const float* m1w1 = (const float*)d_in[1];  const float* m1b1 = (const float*)d_in[2];
  const float* m1w2 = (const float*)d_in[3];  const float* m1b2 = (const float*)d_in[4];
  const float* m1g  = (const float*)d_in[5];  const float* m1be = (const float*)d_in[6];
  const float* m2w1 = (const float*)d_in[7];  const float* m2b1 = (const float*)d_in[8];
  const float* m2w2 = (const float*)d_in[9];  const float* m2b2 = (const float*)d_in[10];
  const float* m2g  = (const float*)d_in[11]; const float* m2be = (const float*)d_in[12];
  const float* m3w1 = (const float*)d_in[13]; const float* m3b1 = (const float*)d_in[14];
  const float* m3w2 = (const float*)d_in[15]; const float* m3b2 = (const float*)d_in[16];
  const float* m3g  = (const float*)d_in[17]; const float* m3be = (const float*)d_in[18];
  const float* m4w1 = (const float*)d_in[19]; const float* m4b1 = (const float*)d_in[20];
  const float* m4w2 = (const float*)d_in[21]; const float* m4b2 = (const float*)d_in[22];
  const float* m4g  = (const float*)d_in[23]; const float* m4be = (const float*)d_in[24];
  const float* wihF = (const float*)d_in[25]; const float* whhF = (const float*)d_in[26];
  const float* bihF = (const float*)d_in[27]; const float* bhhF = (const float*)d_in[28];
  const float* wihR = (const float*)d_in[29]; const float* whhR = (const float*)d_in[30];
  const float* bihR = (const float*)d_in[31]; const float* bhhR = (const float*)d_in[32];
  const float* pw   = (const float*)d_in[33]; const float* pb   = (const float*)d_in[34];
  const float* ew   = (const float*)d_in[35]; const float* eb   = (const float*)d_in[36];

  char* ws = (char*)d_ws;
  float* AUX = (float*)(ws + 0);             // 16 KB reserved
  char*  Xr  = ws + 16384;                   // 6,291,456 B (X1 then X3)
  float* X   = (float*)Xr;
  bf16*  E   = (bf16*)(ws + 16384 + 6291456); // 72,351,744 B (E2 then in-place E4)
  // aliases inside X region, valid AFTER mlp4 has consumed X3:
  float* wihTF = (float*)(Xr + 0);           // 98,304 B
  float* wihTR = (float*)(Xr + 98304);       // 98,304 B
  float* whhTF = (float*)(Xr + 196608);      // 49,152 B
  float* whhTR = (float*)(Xr + 245760);      // 49,152 B -> 294,912
  bf16*  encpF = (bf16*)(Xr + 294912);       // 2,260,992 B
  bf16*  encpR = (bf16*)(Xr + 2555904);      // 2,260,992 B -> 4,816,896 <= 6,291,456

  float* SUM0 = AUX + 0*128;        float* SUM1 = AUX + 1*128;
  float* SUM2 = AUX + 2*128;        float* SUM3 = AUX + 3*128;
  float* SQ0  = AUX + 512 + 0*128;  float* SQ1  = AUX + 512 + 1*128;
  float* SQ2  = AUX + 512 + 2*128;  float* SQ3  = AUX + 512 + 3*128;
  float* SC0  = AUX + 1024 + 0*128; float* SC1  = AUX + 1024 + 1*128;
  float* SC2  = AUX + 1024 + 2*128; float* SC3  = AUX + 1024 + 3*128;
  float* SH0  = AUX + 1536 + 0*128; float* SH1  = AUX + 1536 + 1*128;
  float* SH2  = AUX + 1536 + 2*128; float* SH3  = AUX + 1536 + 3*128;

  float* outP = (float*)d_out;
  float* outE = outP + PRIOR_SZ;
  float* hT   = outP + 2*PRIOR_SZ;

  k_zero<<<1, 256, 0, stream>>>(AUX);
  k_mlp1<<<ROWS1/16, 128, 0, stream>>>(inp, m1w1, m1b1, m1w2, m1b2, X, SUM0, SQ0);
  k_bn<<<1, 128, 0, stream>>>(SUM0, SQ0, m1g, m1be, 1.f/ROWS1, SC0, SH0);
  k_mlp_edge<2*NH><<<ROWS2/16, 128, 0, stream>>>(X, SC0, SH0, nullptr, nullptr, nullptr,
                                                 m2w1, m2b1, m2w2, m2b2, E, SUM1, SQ1);
  k_bn<<<1, 128, 0, stream>>>(SUM1, SQ1, m2g, m2be, 1.f/ROWS2, SC1, SH1);
  k_mlp3<<<ROWS1/16, 128, 0, stream>>>(E, SC1, SH1, m3w1, m3b1, m3w2, m3b2, X, SUM2, SQ2);
  k_bn<<<1, 128, 0, stream>>>(SUM2, SQ2, m3g, m3be, 1.f/ROWS1, SC2, SH2);
  k_mlp_edge<3*NH><<<ROWS2/16, 128, 0, stream>>>(X, SC2, SH2, E, SC1, SH1,
                                                 m4w1, m4b1, m4w2, m4b2, E, SUM3, SQ3);
  k_bn<<<1, 128, 0, stream>>>(SUM3, SQ3, m4g, m4be, 1.f/ROWS2, SC3, SH3);
  // X region is now dead -> transpose GRU weights into it
  k_prep<<<96, 256, 0, stream>>>(wihF, whhF, wihR, whhR, wihTF, whhTF, wihTR, whhTR);
  k_gru<<<2*NSEQ, 64, 0, stream>>>(E, SC3, SH3,
                                   wihTF, whhTF, bihF, bhhF,
                                   wihTR, whhTR, bihR, bhhR,
                                   pw, pb, ew, encpF, encpR, outP, hT);
  k_add<<<(PRIOR_SZ + 255)/256, 256, 0, stream>>>(encpF, encpR, eb, outE);
}

// Round 10
// 2851.248 us; speedup vs baseline: 2.0265x; 1.0453x over previous
//
#include <hip/hip_runtime.h>
#include <hip/hip_bf16.h>
#include <cstring>

// ---- problem constants ----
#define NB 8
#define NT 64
#define NNODE 24
#define ND 6
#define NH 128
#define NR 64
#define NNE 4
#define NEDGE 552                  // NNODE*(NNODE-1)
#define NSEQ (NB*NEDGE)            // 4416
#define ROWS1 (NB*NNODE*NT)        // 12288
#define ROWS2 (NB*NEDGE*NT)        // 282624
#define PRIOR_SZ (NB*NT*NEDGE*NNE) // 1130496

typedef __hip_bfloat16 bf16;
typedef unsigned short u16;
typedef unsigned int u32;

__device__ __forceinline__ float eluf(float x){ return x > 0.f ? x : expm1f(x); }
__device__ __forceinline__ float b2f(bf16 v){ return __bfloat162float(v); }
__device__ __forceinline__ float bflo(u32 u){ return __uint_as_float(u << 16); }
__device__ __forceinline__ float bfhi(u32 u){ return __uint_as_float(u & 0xffff0000u); }
__device__ __forceinline__ u32 packbf2(float a, float b){
  bf16 ha = __float2bfloat16(a), hb = __float2bfloat16(b);
  u16 ua, ub;
  __builtin_memcpy(&ua, &ha, 2); __builtin_memcpy(&ub, &hb, 2);
  return (u32)ua | ((u32)ub << 16);
}

// ---------------- diagnostics / setup ----------------
__global__ void k_fill(float* out, int n, float pat){
  const int i = blockIdx.x*256 + threadIdx.x;
  if(i < n) out[i] = pat;
}
__global__ void k_zero(float* aux){
  for(int i = threadIdx.x; i < 1024; i += 256) aux[i] = 0.f;
}

// transpose GRU weights: wihT[k][row] = wih[row][k] (row in [0,192), k in [0,128))
//                        whhT[k][row] = whh[row][k] (k in [0,64))
__global__ void k_prep(const float* wihF, const float* whhF,
                       const float* wihR, const float* whhR,
                       float* wihTF, float* whhTF, float* wihTR, float* whhTR)
{
  const int i = blockIdx.x*256 + threadIdx.x;
  if(i < 192*128){
    const int r = i / NH, k = i - r*NH;
    wihTF[k*192 + r] = wihF[i];
    wihTR[k*192 + r] = wihR[i];
  }
  if(i < 192*64){
    const int r = i / NR, k = i - r*NR;
    whhTF[k*192 + r] = whhF[i];
    whhTR[k*192 + r] = whhR[i];
  }
}

// ---------------- MLP1: (B,N,T,D)->H->H, pre-BN out + channel sums -------------
__global__ __launch_bounds__(128) void k_mlp1(
    const float* inp, const float* w1, const float* b1,
    const float* w2, const float* b2,
    float* X1, float* sum, float* sq)
{
  const int j = threadIdx.x;
  __shared__ float xin[ND];
  __shared__ float h1[NH];
  const float b1j = b1[j], b2j = b2[j];
  float wcol[ND];
  for(int d = 0; d < ND; d++) wcol[d] = w1[d*NH + j];
  float accS = 0.f, accQ = 0.f;
  const int row0 = blockIdx.x*16;
  for(int r = 0; r < 16; r++){
    const int row = row0 + r;
    const int b = row/(NNODE*NT); const int rem = row - b*(NNODE*NT);
    const int n = rem/NT; const int t = rem - n*NT;
    if(j < ND) xin[j] = inp[((b*NT + t)*NNODE + n)*ND + j];
    __syncthreads();
    float a = b1j;
    for(int d = 0; d < ND; d++) a += xin[d]*wcol[d];
    h1[j] = eluf(a);
    __syncthreads();
    float a2 = b2j;
    for(int k = 0; k < NH; k++) a2 += h1[k]*w2[k*NH + j];
    const float h2 = eluf(a2);
    X1[row*NH + j] = h2; accS += h2; accQ += h2*h2;
    __syncthreads();
  }
  atomicAdd(&sum[j], accS); atomicAdd(&sq[j], accQ);
}

// ---------------- BN params ----------------
__global__ void k_bn(const float* sum, const float* sq,
                     const float* g, const float* be,
                     float inv_cnt, float* sc, float* sh)
{
  const int j = threadIdx.x;
  const float m = sum[j]*inv_cnt;
  const float v = fmaxf(sq[j]*inv_cnt - m*m, 0.f);
  const float s = g[j]*rsqrtf(v + 1e-5f);
  sc[j] = s; sh[j] = be[j] - m*s;
}

// ---------------- edge MLPs (MLP2: KIN=256, MLP4: KIN=384), CH=16 --------------
template<int KIN>
__global__ __launch_bounds__(128) void k_mlp_edge(
  const float* Xn, const float* scN, const float* shN,
  const bf16* Ein, const float* scE, const float* shE,
  const float* w1, const float* b1, const float* w2, const float* b2,
  bf16* Eo, float* sum, float* sq)
{
  const int j = threadIdx.x;
  constexpr int CH = 16, ST = 20;
  __shared__ __align__(16) float xin[KIN][ST];
  __shared__ __align__(16) float h1s[NH][ST];
  const int g0 = blockIdx.x*CH;
  const int b = g0/(NEDGE*NT); const int rem = g0 - b*(NEDGE*NT);
  const int e = rem/NT; const int t0 = rem - e*NT;
  const int snd = e/23, r0 = e - snd*23;
  const int rcv = r0 + (r0 >= snd ? 1 : 0);
  const float sN = scN[j], tN = shN[j];
  float sE = 0.f, tE = 0.f;
  if constexpr(KIN == 3*NH){ sE = scE[j]; tE = shE[j]; }
  const int baseS = ((b*NNODE + snd)*NT + t0)*NH;
  const int baseR = ((b*NNODE + rcv)*NT + t0)*NH;
  for(int r = 0; r < CH; r++){
    xin[j][r]      = Xn[baseS + r*NH + j]*sN + tN;
    xin[NH + j][r] = Xn[baseR + r*NH + j]*sN + tN;
    if constexpr(KIN == 3*NH)
      xin[2*NH + j][r] = b2f(Ein[(size_t)(g0 + r)*NH + j])*sE + tE;
  }
  __syncthreads();
  float acc[CH];
  const float b1j = b1[j];
  #pragma unroll
  for(int r = 0; r < CH; r++) acc[r] = b1j;
  for(int k = 0; k < KIN; k++){
    const float wv = w1[k*NH + j];
    const float4 xa = *(const float4*)&xin[k][0];
    const float4 xb = *(const float4*)&xin[k][4];
    const float4 xc = *(const float4*)&xin[k][8];
    const float4 xd = *(const float4*)&xin[k][12];
    acc[0]  += xa.x*wv; acc[1]  += xa.y*wv; acc[2]  += xa.z*wv; acc[3]  += xa.w*wv;
    acc[4]  += xb.x*wv; acc[5]  += xb.y*wv; acc[6]  += xb.z*wv; acc[7]  += xb.w*wv;
    acc[8]  += xc.x*wv; acc[9]  += xc.y*wv; acc[10] += xc.z*wv; acc[11] += xc.w*wv;
    acc[12] += xd.x*wv; acc[13] += xd.y*wv; acc[14] += xd.z*wv; acc[15] += xd.w*wv;
  }
  #pragma unroll
  for(int r = 0; r < CH; r++) h1s[j][r] = eluf(acc[r]);
  __syncthreads();
  const float b2j = b2[j];
  #pragma unroll
  for(int r = 0; r < CH; r++) acc[r] = b2j;
  for(int k = 0; k < NH; k++){
    const float wv = w2[k*NH + j];
    const float4 xa = *(const float4*)&h1s[k][0];
    const float4 xb = *(const float4*)&h1s[k][4];
    const float4 xc = *(const float4*)&h1s[k][8];
    const float4 xd = *(const float4*)&h1s[k][12];
    acc[0]  += xa.x*wv; acc[1]  += xa.y*wv; acc[2]  += xa.z*wv; acc[3]  += xa.w*wv;
    acc[4]  += xb.x*wv; acc[5]  += xb.y*wv; acc[6]  += xb.z*wv; acc[7]  += xb.w*wv;
    acc[8]  += xc.x*wv; acc[9]  += xc.y*wv; acc[10] += xc.z*wv; acc[11] += xc.w*wv;
    acc[12] += xd.x*wv; acc[13] += xd.y*wv; acc[14] += xd.z*wv; acc[15] += xd.w*wv;
  }
  float accS = 0.f, accQ = 0.f;
  #pragma unroll
  for(int r = 0; r < CH; r++){
    const float h2 = eluf(acc[r]);
    Eo[(size_t)(g0 + r)*NH + j] = __float2bfloat16(h2);
    accS += h2; accQ += h2*h2;
  }
  atomicAdd(&sum[j], accS); atomicAdd(&sq[j], accQ);
}

// ---------------- agg (mean over incoming edges) + MLP3 ----------------
__global__ __launch_bounds__(128) void k_mlp3(
    const bf16* Ein, const float* scE, const float* shE,
    const float* w1, const float* b1, const float* w2, const float* b2,
    float* X3, float* sum, float* sq)
{
  const int j = threadIdx.x;
  __shared__ float xin[NH];
  __shared__ float h1[NH];
  const float sE = scE[j], tE = shE[j];
  float accS = 0.f, accQ = 0.f;
  const int row0 = blockIdx.x*16;
  for(int r = 0; r < 16; r++){
    const int row = row0 + r;
    const int b = row/(NNODE*NT); const int rem = row - b*(NNODE*NT);
    const int n = rem/NT; const int t = rem - n*NT;
    float s = 0.f;
    for(int i = 0; i < NNODE; i++){
      if(i == n) continue;
      const int e = i*23 + (n < i ? n : n - 1);
      s += b2f(Ein[((size_t)(b*NEDGE + e)*NT + t)*NH + j]);
    }
    xin[j] = sE*s*(1.f/23.f) + tE;
    __syncthreads();
    float a = b1[j];
    for(int k = 0; k < NH; k++) a += xin[k]*w1[k*NH + j];
    h1[j] = eluf(a);
    __syncthreads();
    float a2 = b2[j];
    for(int k = 0; k < NH; k++) a2 += h1[k]*w2[k*NH + j];
    const float h2 = eluf(a2);
    X3[row*NH + j] = h2; accS += h2; accQ += h2*h2;
    __syncthreads();
  }
  atomicAdd(&sum[j], accS); atomicAdd(&sq[j], accQ);
}

// ---------------- GRU: 2 independent (seq,dir) units per 128-thread block -----
// Wave u handles unit gid = blockIdx.x*2 + u. All LDS is wave-private (indexed
// by u), so NO barriers are needed anywhere: same-wave DS ops are pipeline-
// ordered, and the compiler preserves program order for may-aliasing LDS
// accesses. 4 chunks of 16 steps: stage x -> xw GEMM chunk -> 16 recurrence
// steps. whhT packed bf16 in registers; h fp32 in LDS; history bf16 in LDS.
// Epilogue: lane p projects timestep p. LDS total = 37,888 B -> 4 blocks/CU.
__global__ __launch_bounds__(128) void k_gru(
  const bf16* E4, const float* sc4, const float* sh4,
  const float* wihTF, const float* whhTF, const float* bihF, const float* bhhF,
  const float* wihTR, const float* whhTR, const float* bihR, const float* bhhR,
  const float* pw, const float* pb, const float* ew,
  bf16* encpF, bf16* encpR, float* outP, float* hT)
{
  __shared__ __align__(16) bf16 xst[2][NH][16];    // 8192 B
  __shared__ __align__(16) bf16 xwb[2][16][192];   // 12288 B
  __shared__ __align__(16) bf16 hist[2][NT][66];   // 16896 B
  __shared__ __align__(16) float hs[2][NR];        // 512 B
  const int tid = threadIdx.x;
  const int u = tid >> 6, c = tid & 63;
  const int gid = blockIdx.x*2 + u;
  const int dir = (gid >= NSEQ) ? 1 : 0;
  const int s = dir ? (gid - NSEQ) : gid;
  const int sb = s / NEDGE, se = s - sb*NEDGE;
  const float* wihT = dir ? wihTR : wihTF;
  const float* whhT = dir ? whhTR : whhTF;
  const float* bih  = dir ? bihR  : bihF;
  const float* bhh  = dir ? bhhR  : bhhF;
  const float bxr = bih[c], bxz = bih[64+c], bxn = bih[128+c];
  const float bhr = bhh[c], bhz = bhh[64+c], bhn = bhh[128+c];
  const float sc_a = sc4[c], sc_b = sc4[c+64];
  const float sh_a = sh4[c], sh_b = sh4[c+64];

  // whhT into registers (packed bf16x2)
  u32 wr2[32], wz2[32], wn2[32];
  #pragma unroll
  for(int kk = 0; kk < 32; kk++){
    wr2[kk] = packbf2(whhT[(2*kk)*192 + c],        whhT[(2*kk+1)*192 + c]);
    wz2[kk] = packbf2(whhT[(2*kk)*192 + 64 + c],   whhT[(2*kk+1)*192 + 64 + c]);
    wn2[kk] = packbf2(whhT[(2*kk)*192 + 128 + c],  whhT[(2*kk+1)*192 + 128 + c]);
  }

  hs[u][c] = 0.f;
  float hprev = 0.f;

  for(int T = 0; T < 4; T++){
    // ---- stage 16 timesteps of x (proc order) ----
    for(int tp = 0; tp < 16; tp++){
      const int p = T*16 + tp;
      const int t = dir ? (NT - 1 - p) : p;
      const size_t xb = ((size_t)s*NT + t)*NH;
      xst[u][c][tp]      = __float2bfloat16(b2f(E4[xb + c])*sc_a + sh_a);
      xst[u][c + 64][tp] = __float2bfloat16(b2f(E4[xb + c + 64])*sc_b + sh_b);
    }
    // ---- xw GEMM chunk: 16 steps x 3 gates for this lane's channel ----
    float ar[16], az[16], an[16];
    #pragma unroll
    for(int tp = 0; tp < 16; tp++){ ar[tp] = bxr; az[tp] = bxz; an[tp] = bxn; }
    for(int k = 0; k < NH; k++){
      const float wr = wihT[k*192 + c];
      const float wz = wihT[k*192 + 64 + c];
      const float wn = wihT[k*192 + 128 + c];
      const uint4 q0 = *(const uint4*)&xst[u][k][0];
      const uint4 q1 = *(const uint4*)&xst[u][k][8];
      float xv[16];
      xv[0]=bflo(q0.x); xv[1]=bfhi(q0.x); xv[2]=bflo(q0.y); xv[3]=bfhi(q0.y);
      xv[4]=bflo(q0.z); xv[5]=bfhi(q0.z); xv[6]=bflo(q0.w); xv[7]=bfhi(q0.w);
      xv[8]=bflo(q1.x); xv[9]=bfhi(q1.x); xv[10]=bflo(q1.y); xv[11]=bfhi(q1.y);
      xv[12]=bflo(q1.z); xv[13]=bfhi(q1.z); xv[14]=bflo(q1.w); xv[15]=bfhi(q1.w);
      #pragma unroll
      for(int tp = 0; tp < 16; tp++){
        ar[tp] += xv[tp]*wr; az[tp] += xv[tp]*wz; an[tp] += xv[tp]*wn;
      }
    }
    #pragma unroll
    for(int tp = 0; tp < 16; tp++){
      xwb[u][tp][c]       = __float2bfloat16(ar[tp]);
      xwb[u][tp][64 + c]  = __float2bfloat16(az[tp]);
      xwb[u][tp][128 + c] = __float2bfloat16(an[tp]);
    }
    // ---- 16 recurrence steps ----
    for(int pp = 0; pp < 16; pp++){
      const float xr = b2f(xwb[u][pp][c]);
      const float xz = b2f(xwb[u][pp][64 + c]);
      const float xn = b2f(xwb[u][pp][128 + c]);
      float hr = bhr, hz = bhz, hn = bhn;
      #pragma unroll
      for(int kk = 0; kk < 16; kk++){
        const float4 hp = *(const float4*)&hs[u][4*kk];
        const u32 ur0 = wr2[2*kk], ur1 = wr2[2*kk+1];
        const u32 uz0 = wz2[2*kk], uz1 = wz2[2*kk+1];
        const u32 un0 = wn2[2*kk], un1 = wn2[2*kk+1];
        hr += hp.x*bflo(ur0) + hp.y*bfhi(ur0) + hp.z*bflo(ur1) + hp.w*bfhi(ur1);
        hz += hp.x*bflo(uz0) + hp.y*bfhi(uz0) + hp.z*bflo(uz1) + hp.w*bfhi(uz1);
        hn += hp.x*bflo(un0) + hp.y*bfhi(un0) + hp.z*bflo(un1) + hp.w*bfhi(un1);
      }
      const float rg = 1.f/(1.f + expf(-(xr + hr)));
      const float zg = 1.f/(1.f + expf(-(xz + hz)));
      const float ng = tanhf(xn + rg*hn);
      const float hnew = (1.f - zg)*ng + zg*hprev;
      hs[u][c] = hnew; hprev = hnew;
      hist[u][T*16 + pp][c] = __float2bfloat16(hnew);
    }
  }
  if(!dir) hT[(size_t)s*NR + c] = hprev;

  // ---- epilogue: projections; lane c owns proc step p = c ----
  const int t = dir ? (NT - 1 - c) : c;
  if(!dir){
    float ap[NNE] = {pb[0], pb[1], pb[2], pb[3]};
    float ae[NNE] = {0.f, 0.f, 0.f, 0.f};
    for(int kk = 0; kk < 32; kk++){
      u32 hp; __builtin_memcpy(&hp, &hist[u][c][2*kk], 4);
      const float h0 = bflo(hp), h1 = bfhi(hp);
      #pragma unroll
      for(int l = 0; l < NNE; l++){
        ap[l] += h0*pw[(2*kk)*NNE + l] + h1*pw[(2*kk+1)*NNE + l];
        ae[l] += h0*ew[(2*kk)*NNE + l] + h1*ew[(2*kk+1)*NNE + l];
      }
    }
    float4 pv = {ap[0], ap[1], ap[2], ap[3]};
    *(float4*)&outP[(((size_t)(sb*NT + t))*NEDGE + se)*NNE] = pv;
    u32 e01 = packbf2(ae[0], ae[1]), e23 = packbf2(ae[2], ae[3]);
    u32* ed = (u32*)&encpF[((size_t)s*NT + t)*NNE];
    ed[0] = e01; ed[1] = e23;
  } else {
    float ae[NNE] = {0.f, 0.f, 0.f, 0.f};
    for(int kk = 0; kk < 32; kk++){
      u32 hp; __builtin_memcpy(&hp, &hist[u][c][2*kk], 4);
      const float h0 = bflo(hp), h1 = bfhi(hp);
      #pragma unroll
      for(int l = 0; l < NNE; l++){
        ae[l] += h0*ew[(NR + 2*kk)*NNE + l] + h1*ew[(NR + 2*kk+1)*NNE + l];
      }
    }
    u32 e01 = packbf2(ae[0], ae[1]), e23 = packbf2(ae[2], ae[3]);
    u32* ed = (u32*)&encpR[((size_t)s*NT + t)*NNE];
    ed[0] = e01; ed[1] = e23;
  }
}

// ---------------- merge enc halves + bias ----------------
__global__ void k_add(const bf16* eF, const bf16* eR, const float* eb, float* outE){
  const int i = blockIdx.x*256 + threadIdx.x;
  if(i >= PRIOR_SZ) return;
  const int l = i & 3; const int r2 = i >> 2;
  const int e = r2 % NEDGE; const int r3 = r2 / NEDGE;
  const int t = r3 % NT; const int b = r3 / NT;
  const int s = b*NEDGE + e;
  const size_t src = ((size_t)s*NT + t)*NNE + l;
  outE[i] = b2f(eF[src]) + b2f(eR[src]) + eb[l];
}

extern "C" void kernel_launch(void* const* d_in, const int* in_sizes, int n_in,
                              void* d_out, int out_size, void* d_ws, size_t ws_size,
                              hipStream_t stream)
{
  const size_t NEED = 78659584ull;
  if(ws_size < NEED){
    k_fill<<<(out_size + 255)/256, 256, 0, stream>>>((float*)d_out, out_size, 3584.0f);
    return;
  }
  const float* inp  = (const float*)d_in[0];
  const float* m1w1 = (const float*)d_in[1];  const float* m1b1 = (const float*)d_in[2];
  const float* m1w2 = (const float*)d_in[3];  const float* m1b2 = (const float*)d_in[4];
  const float* m1g  = (const float*)d_in[5];  const float* m1be = (const float*)d_in[6];
  const float* m2w1 = (const float*)d_in[7];  const float* m2b1 = (const float*)d_in[8];
  const float* m2w2 = (const float*)d_in[9];  const float* m2b2 = (const float*)d_in[10];
  const float* m2g  = (const float*)d_in[11]; const float* m2be = (const float*)d_in[12];
  const float* m3w1 = (const float*)d_in[13]; const float* m3b1 = (const float*)d_in[14];
  const float* m3w2 = (const float*)d_in[15]; const float* m3b2 = (const float*)d_in[16];
  const float* m3g  = (const float*)d_in[17]; const float* m3be = (const float*)d_in[18];
  const float* m4w1 = (const float*)d_in[19]; const float* m4b1 = (const float*)d_in[20];
  const float* m4w2 = (const float*)d_in[21]; const float* m4b2 = (const float*)d_in[22];
  const float* m4g  = (const float*)d_in[23]; const float* m4be = (const float*)d_in[24];
  const float* wihF = (const float*)d_in[25]; const float* whhF = (const float*)d_in[26];
  const float* bihF = (const float*)d_in[27]; const float* bhhF = (const float*)d_in[28];
  const float* wihR = (const float*)d_in[29]; const float* whhR = (const float*)d_in[30];
  const float* bihR = (const float*)d_in[31]; const float* bhhR = (const float*)d_in[32];
  const float* pw   = (const float*)d_in[33]; const float* pb   = (const float*)d_in[34];
  const float* ew   = (const float*)d_in[35]; const float* eb   = (const float*)d_in[36];

  char* ws = (char*)d_ws;
  float* AUX = (float*)(ws + 0);             // 16 KB reserved
  char*  Xr  = ws + 16384;                   // 6,291,456 B (X1 then X3)
  float* X   = (float*)Xr;
  bf16*  E   = (bf16*)(ws + 16384 + 6291456); // 72,351,744 B (E2 then in-place E4)
  // aliases inside X region, valid AFTER mlp4 has consumed X3:
  float* wihTF = (float*)(Xr + 0);           // 98,304 B
  float* wihTR = (float*)(Xr + 98304);       // 98,304 B
  float* whhTF = (float*)(Xr + 196608);      // 49,152 B
  float* whhTR = (float*)(Xr + 245760);      // 49,152 B -> 294,912
  bf16*  encpF = (bf16*)(Xr + 294912);       // 2,260,992 B
  bf16*  encpR = (bf16*)(Xr + 2555904);      // 2,260,992 B -> 4,816,896 <= 6,291,456

  float* SUM0 = AUX + 0*128;        float* SUM1 = AUX + 1*128;
  float* SUM2 = AUX + 2*128;        float* SUM3 = AUX + 3*128;
  float* SQ0  = AUX + 512 + 0*128;  float* SQ1  = AUX + 512 + 1*128;
  float* SQ2  = AUX + 512 + 2*128;  float* SQ3  = AUX + 512 + 3*128;
  float* SC0  = AUX + 1024 + 0*128; float* SC1  = AUX + 1024 + 1*128;
  float* SC2  = AUX + 1024 + 2*128; float* SC3  = AUX + 1024 + 3*128;
  float* SH0  = AUX + 1536 + 0*128; float* SH1  = AUX + 1536 + 1*128;
  float* SH2  = AUX + 1536 + 2*128; float* SH3  = AUX + 1536 + 3*128;

  float* outP = (float*)d_out;
  float* outE = outP + PRIOR_SZ;
  float* hT   = outP + 2*PRIOR_SZ;

  k_zero<<<1, 256, 0, stream>>>(AUX);
  k_mlp1<<<ROWS1/16, 128, 0, stream>>>(inp, m1w1, m1b1, m1w2, m1b2, X, SUM0, SQ0);
  k_bn<<<1, 128, 0, stream>>>(SUM0, SQ0, m1g, m1be, 1.f/ROWS1, SC0, SH0);
  k_mlp_edge<2*NH><<<ROWS2/16, 128, 0, stream>>>(X, SC0, SH0, nullptr, nullptr, nullptr,
                                                 m2w1, m2b1, m2w2, m2b2, E, SUM1, SQ1);
  k_bn<<<1, 128, 0, stream>>>(SUM1, SQ1, m2g, m2be, 1.f/ROWS2, SC1, SH1);
  k_mlp3<<<ROWS1/16, 128, 0, stream>>>(E, SC1, SH1, m3w1, m3b1, m3w2, m3b2, X, SUM2, SQ2);
  k_bn<<<1, 128, 0, stream>>>(SUM2, SQ2, m3g, m3be, 1.f/ROWS1, SC2, SH2);
  k_mlp_edge<3*NH><<<ROWS2/16, 128, 0, stream>>>(X, SC2, SH2, E, SC1, SH1,
                                                 m4w1, m4b1, m4w2, m4b2, E, SUM3, SQ3);
  k_bn<<<1, 128, 0, stream>>>(SUM3, SQ3, m4g, m4be, 1.f/ROWS2, SC3, SH3);
  // X region is now dead -> transpose GRU weights into it
  k_prep<<<96, 256, 0, stream>>>(wihF, whhF, wihR, whhR, wihTF, whhTF, wihTR, whhTR);
  k_gru<<<NSEQ, 128, 0, stream>>>(E, SC3, SH3,
                                  wihTF, whhTF, bihF, bhhF,
                                  wihTR, whhTR, bihR, bhhR,
                                  pw, pb, ew, encpF, encpR, outP, hT);
  k_add<<<(PRIOR_SZ + 255)/256, 256, 0, stream>>>(encpF, encpR, eb, outE);
}

// Round 11
// 2020.992 us; speedup vs baseline: 2.8590x; 1.4108x over previous
//
#include <hip/hip_runtime.h>
#include <hip/hip_bf16.h>
#include <cstring>

// ---- problem constants ----
#define NB 8
#define NT 64
#define NNODE 24
#define ND 6
#define NH 128
#define NR 64
#define NNE 4
#define NEDGE 552                  // NNODE*(NNODE-1)
#define NSEQ (NB*NEDGE)            // 4416
#define ROWS1 (NB*NNODE*NT)        // 12288
#define ROWS2 (NB*NEDGE*NT)        // 282624
#define PRIOR_SZ (NB*NT*NEDGE*NNE) // 1130496

typedef __hip_bfloat16 bf16;
typedef unsigned short u16;
typedef unsigned int u32;
typedef _Float16 f16;
typedef __attribute__((ext_vector_type(2))) _Float16 f16x2;

__device__ __forceinline__ float eluf(float x){ return x > 0.f ? x : expm1f(x); }
__device__ __forceinline__ float b2f(bf16 v){ return __bfloat162float(v); }
__device__ __forceinline__ u16 f2h(float x){ f16 h = (f16)x; u16 v; __builtin_memcpy(&v, &h, 2); return v; }
__device__ __forceinline__ float h2f(u16 v){ f16 h; __builtin_memcpy(&h, &v, 2); return (float)h; }
__device__ __forceinline__ u32 packf2(float a, float b){ return (u32)f2h(a) | ((u32)f2h(b) << 16); }

#if defined(__has_builtin)
#if __has_builtin(__builtin_amdgcn_fdot2)
#define HAS_DOT2 1
#endif
#endif

#ifdef HAS_DOT2
__device__ __forceinline__ float dot2(u32 a, u32 b, float c){
  f16x2 av, bv;
  __builtin_memcpy(&av, &a, 4); __builtin_memcpy(&bv, &b, 4);
  return __builtin_amdgcn_fdot2(av, bv, c, false);
}
#else
__device__ __forceinline__ float dot2(u32 a, u32 b, float c){
  return c + h2f((u16)a)*h2f((u16)b) + h2f((u16)(a>>16))*h2f((u16)(b>>16));
}
#endif

// ---------------- diagnostics / setup ----------------
__global__ void k_fill(float* out, int n, float pat){
  const int i = blockIdx.x*256 + threadIdx.x;
  if(i < n) out[i] = pat;
}
__global__ void k_zero(float* aux){
  for(int i = threadIdx.x; i < 1024; i += 256) aux[i] = 0.f;
}

// pack GRU weights as pair-transposed f16x2:
//  wihP[k2*192 + r] = (wih[r][2k2], wih[r][2k2+1])   k2 in [0,64), r in [0,192)
//  whhP[k2*192 + r] = (whh[r][2k2], whh[r][2k2+1])   k2 in [0,32)
__global__ void k_prep(const float* wihF, const float* whhF,
                       const float* wihR, const float* whhR,
                       u32* wihPF, u32* whhPF, u32* wihPR, u32* whhPR)
{
  const int i = blockIdx.x*256 + threadIdx.x;
  if(i < 192*64){
    const int r = i >> 6, k2 = i & 63;
    wihPF[k2*192 + r] = packf2(wihF[r*NH + 2*k2], wihF[r*NH + 2*k2 + 1]);
    wihPR[k2*192 + r] = packf2(wihR[r*NH + 2*k2], wihR[r*NH + 2*k2 + 1]);
  }
  if(i < 192*32){
    const int r = i >> 5, k2 = i & 31;
    whhPF[k2*192 + r] = packf2(whhF[r*NR + 2*k2], whhF[r*NR + 2*k2 + 1]);
    whhPR[k2*192 + r] = packf2(whhR[r*NR + 2*k2], whhR[r*NR + 2*k2 + 1]);
  }
}

// ---------------- MLP1: (B,N,T,D)->H->H, pre-BN out + channel sums -------------
__global__ __launch_bounds__(128) void k_mlp1(
    const float* inp, const float* w1, const float* b1,
    const float* w2, const float* b2,
    float* X1, float* sum, float* sq)
{
  const int j = threadIdx.x;
  __shared__ float xin[ND];
  __shared__ float h1[NH];
  const float b1j = b1[j], b2j = b2[j];
  float wcol[ND];
  for(int d = 0; d < ND; d++) wcol[d] = w1[d*NH + j];
  float accS = 0.f, accQ = 0.f;
  const int row0 = blockIdx.x*16;
  for(int r = 0; r < 16; r++){
    const int row = row0 + r;
    const int b = row/(NNODE*NT); const int rem = row - b*(NNODE*NT);
    const int n = rem/NT; const int t = rem - n*NT;
    if(j < ND) xin[j] = inp[((b*NT + t)*NNODE + n)*ND + j];
    __syncthreads();
    float a = b1j;
    for(int d = 0; d < ND; d++) a += xin[d]*wcol[d];
    h1[j] = eluf(a);
    __syncthreads();
    float a2 = b2j;
    for(int k = 0; k < NH; k++) a2 += h1[k]*w2[k*NH + j];
    const float h2 = eluf(a2);
    X1[row*NH + j] = h2; accS += h2; accQ += h2*h2;
    __syncthreads();
  }
  atomicAdd(&sum[j], accS); atomicAdd(&sq[j], accQ);
}

// ---------------- BN params ----------------
__global__ void k_bn(const float* sum, const float* sq,
                     const float* g, const float* be,
                     float inv_cnt, float* sc, float* sh)
{
  const int j = threadIdx.x;
  const float m = sum[j]*inv_cnt;
  const float v = fmaxf(sq[j]*inv_cnt - m*m, 0.f);
  const float s = g[j]*rsqrtf(v + 1e-5f);
  sc[j] = s; sh[j] = be[j] - m*s;
}

// ---------------- edge MLPs (MLP2: KIN=256, MLP4: KIN=384), CH=16 --------------
template<int KIN>
__global__ __launch_bounds__(128) void k_mlp_edge(
  const float* Xn, const float* scN, const float* shN,
  const bf16* Ein, const float* scE, const float* shE,
  const float* w1, const float* b1, const float* w2, const float* b2,
  bf16* Eo, float* sum, float* sq)
{
  const int j = threadIdx.x;
  constexpr int CH = 16, ST = 20;
  __shared__ __align__(16) float xin[KIN][ST];
  __shared__ __align__(16) float h1s[NH][ST];
  const int g0 = blockIdx.x*CH;
  const int b = g0/(NEDGE*NT); const int rem = g0 - b*(NEDGE*NT);
  const int e = rem/NT; const int t0 = rem - e*NT;
  const int snd = e/23, r0 = e - snd*23;
  const int rcv = r0 + (r0 >= snd ? 1 : 0);
  const float sN = scN[j], tN = shN[j];
  float sE = 0.f, tE = 0.f;
  if constexpr(KIN == 3*NH){ sE = scE[j]; tE = shE[j]; }
  const int baseS = ((b*NNODE + snd)*NT + t0)*NH;
  const int baseR = ((b*NNODE + rcv)*NT + t0)*NH;
  for(int r = 0; r < CH; r++){
    xin[j][r]      = Xn[baseS + r*NH + j]*sN + tN;
    xin[NH + j][r] = Xn[baseR + r*NH + j]*sN + tN;
    if constexpr(KIN == 3*NH)
      xin[2*NH + j][r] = b2f(Ein[(size_t)(g0 + r)*NH + j])*sE + tE;
  }
  __syncthreads();
  float acc[CH];
  const float b1j = b1[j];
  #pragma unroll
  for(int r = 0; r < CH; r++) acc[r] = b1j;
  for(int k = 0; k < KIN; k++){
    const float wv = w1[k*NH + j];
    const float4 xa = *(const float4*)&xin[k][0];
    const float4 xb = *(const float4*)&xin[k][4];
    const float4 xc = *(const float4*)&xin[k][8];
    const float4 xd = *(const float4*)&xin[k][12];
    acc[0]  += xa.x*wv; acc[1]  += xa.y*wv; acc[2]  += xa.z*wv; acc[3]  += xa.w*wv;
    acc[4]  += xb.x*wv; acc[5]  += xb.y*wv; acc[6]  += xb.z*wv; acc[7]  += xb.w*wv;
    acc[8]  += xc.x*wv; acc[9]  += xc.y*wv; acc[10] += xc.z*wv; acc[11] += xc.w*wv;
    acc[12] += xd.x*wv; acc[13] += xd.y*wv; acc[14] += xd.z*wv; acc[15] += xd.w*wv;
  }
  #pragma unroll
  for(int r = 0; r < CH; r++) h1s[j][r] = eluf(acc[r]);
  __syncthreads();
  const float b2j = b2[j];
  #pragma unroll
  for(int r = 0; r < CH; r++) acc[r] = b2j;
  for(int k = 0; k < NH; k++){
    const float wv = w2[k*NH + j];
    const float4 xa = *(const float4*)&h1s[k][0];
    const float4 xb = *(const float4*)&h1s[k][4];
    const float4 xc = *(const float4*)&h1s[k][8];
    const float4 xd = *(const float4*)&h1s[k][12];
    acc[0]  += xa.x*wv; acc[1]  += xa.y*wv; acc[2]  += xa.z*wv; acc[3]  += xa.w*wv;
    acc[4]  += xb.x*wv; acc[5]  += xb.y*wv; acc[6]  += xb.z*wv; acc[7]  += xb.w*wv;
    acc[8]  += xc.x*wv; acc[9]  += xc.y*wv; acc[10] += xc.z*wv; acc[11] += xc.w*wv;
    acc[12] += xd.x*wv; acc[13] += xd.y*wv; acc[14] += xd.z*wv; acc[15] += xd.w*wv;
  }
  float accS = 0.f, accQ = 0.f;
  #pragma unroll
  for(int r = 0; r < CH; r++){
    const float h2 = eluf(acc[r]);
    Eo[(size_t)(g0 + r)*NH + j] = __float2bfloat16(h2);
    accS += h2; accQ += h2*h2;
  }
  atomicAdd(&sum[j], accS); atomicAdd(&sq[j], accQ);
}

// ---------------- agg (mean over incoming edges) + MLP3 ----------------
__global__ __launch_bounds__(128) void k_mlp3(
    const bf16* Ein, const float* scE, const float* shE,
    const float* w1, const float* b1, const float* w2, const float* b2,
    float* X3, float* sum, float* sq)
{
  const int j = threadIdx.x;
  __shared__ float xin[NH];
  __shared__ float h1[NH];
  const float sE = scE[j], tE = shE[j];
  float accS = 0.f, accQ = 0.f;
  const int row0 = blockIdx.x*16;
  for(int r = 0; r < 16; r++){
    const int row = row0 + r;
    const int b = row/(NNODE*NT); const int rem = row - b*(NNODE*NT);
    const int n = rem/NT; const int t = rem - n*NT;
    float s = 0.f;
    for(int i = 0; i < NNODE; i++){
      if(i == n) continue;
      const int e = i*23 + (n < i ? n : n - 1);
      s += b2f(Ein[((size_t)(b*NEDGE + e)*NT + t)*NH + j]);
    }
    xin[j] = sE*s*(1.f/23.f) + tE;
    __syncthreads();
    float a = b1[j];
    for(int k = 0; k < NH; k++) a += xin[k]*w1[k*NH + j];
    h1[j] = eluf(a);
    __syncthreads();
    float a2 = b2[j];
    for(int k = 0; k < NH; k++) a2 += h1[k]*w2[k*NH + j];
    const float h2 = eluf(a2);
    X3[row*NH + j] = h2; accS += h2; accQ += h2*h2;
    __syncthreads();
  }
  atomicAdd(&sum[j], accS); atomicAdd(&sq[j], accQ);
}

// ---------------- GRU: 2 independent (seq,dir) units per 128-thread block -----
// f16 data path with v_dot2_f32_f16 (2 MAC/inst, fp32 accum). Wave-private LDS
// (indexed by u) => NO barriers: same-wave DS ops are pipeline-ordered.
// 4 chunks of 16 steps: stage x (f16, [tp][k] layout) -> xw GEMM chunk (dot2,
// uint4 broadcast x reads) -> 16 recurrence steps (h f16 in LDS, whh f16x2 in
// registers, dot2). History f16 in LDS; epilogue lane p projects step p.
// LDS total = 37,632 B.
__global__ __launch_bounds__(128) void k_gru(
  const bf16* E4, const float* sc4, const float* sh4,
  const u32* wihPF, const u32* whhPF, const float* bihF, const float* bhhF,
  const u32* wihPR, const u32* whhPR, const float* bihR, const float* bhhR,
  const float* pw, const float* pb, const float* ew,
  bf16* encpF, bf16* encpR, float* outP, float* hT)
{
  __shared__ __align__(16) u16 xst16[2][16][NH];   // 8192 B  (f16 bits, [tp][k])
  __shared__ __align__(16) u16 xwb16[2][16][192];  // 12288 B
  __shared__ __align__(16) u16 hist16[2][NT][66];  // 16896 B
  __shared__ __align__(16) u16 hs16[2][NR];        // 256 B
  const int tid = threadIdx.x;
  const int u = tid >> 6, c = tid & 63;
  const int gid = blockIdx.x*2 + u;
  const int dir = (gid >= NSEQ) ? 1 : 0;
  const int s = dir ? (gid - NSEQ) : gid;
  const int sb = s / NEDGE, se = s - sb*NEDGE;
  const u32* wihP = dir ? wihPR : wihPF;
  const u32* whhP = dir ? whhPR : whhPF;
  const float* bih = dir ? bihR : bihF;
  const float* bhh = dir ? bhhR : bhhF;
  const float bxr = bih[c], bxz = bih[64+c], bxn = bih[128+c];
  const float bhr = bhh[c], bhz = bhh[64+c], bhn = bhh[128+c];
  const float sc_a = sc4[c], sc_b = sc4[c+64];
  const float sh_a = sh4[c], sh_b = sh4[c+64];

  // whhP pairs into registers (96 u32)
  u32 wr2[32], wz2[32], wn2[32];
  #pragma unroll
  for(int kk = 0; kk < 32; kk++){
    wr2[kk] = whhP[kk*192 + c];
    wz2[kk] = whhP[kk*192 + 64 + c];
    wn2[kk] = whhP[kk*192 + 128 + c];
  }

  hs16[u][c] = 0;
  float hprev = 0.f;

  for(int T = 0; T < 4; T++){
    // ---- stage 16 timesteps of x (proc order) as f16 [tp][k] ----
    for(int tp = 0; tp < 16; tp++){
      const int p = T*16 + tp;
      const int t = dir ? (NT - 1 - p) : p;
      const size_t xb = ((size_t)s*NT + t)*NH;
      xst16[u][tp][c]      = f2h(b2f(E4[xb + c])*sc_a + sh_a);
      xst16[u][tp][c + 64] = f2h(b2f(E4[xb + c + 64])*sc_b + sh_b);
    }
    // ---- xw GEMM chunk via dot2: 16 steps x 3 gates ----
    float ar[16], az[16], an[16];
    #pragma unroll
    for(int tp = 0; tp < 16; tp++){ ar[tp] = bxr; az[tp] = bxz; an[tp] = bxn; }
    for(int kb = 0; kb < 16; kb++){
      u32 wr[4], wz[4], wn[4];
      #pragma unroll
      for(int j = 0; j < 4; j++){
        const u32* wp = wihP + (size_t)(4*kb + j)*192;
        wr[j] = wp[c]; wz[j] = wp[64 + c]; wn[j] = wp[128 + c];
      }
      #pragma unroll
      for(int tp = 0; tp < 16; tp++){
        const uint4 xq = *(const uint4*)&xst16[u][tp][8*kb];
        ar[tp] = dot2(xq.x, wr[0], ar[tp]); ar[tp] = dot2(xq.y, wr[1], ar[tp]);
        ar[tp] = dot2(xq.z, wr[2], ar[tp]); ar[tp] = dot2(xq.w, wr[3], ar[tp]);
        az[tp] = dot2(xq.x, wz[0], az[tp]); az[tp] = dot2(xq.y, wz[1], az[tp]);
        az[tp] = dot2(xq.z, wz[2], az[tp]); az[tp] = dot2(xq.w, wz[3], az[tp]);
        an[tp] = dot2(xq.x, wn[0], an[tp]); an[tp] = dot2(xq.y, wn[1], an[tp]);
        an[tp] = dot2(xq.z, wn[2], an[tp]); an[tp] = dot2(xq.w, wn[3], an[tp]);
      }
    }
    #pragma unroll
    for(int tp = 0; tp < 16; tp++){
      xwb16[u][tp][c]       = f2h(ar[tp]);
      xwb16[u][tp][64 + c]  = f2h(az[tp]);
      xwb16[u][tp][128 + c] = f2h(an[tp]);
    }
    // ---- 16 recurrence steps ----
    for(int pp = 0; pp < 16; pp++){
      const float xr = h2f(xwb16[u][pp][c]);
      const float xz = h2f(xwb16[u][pp][64 + c]);
      const float xn = h2f(xwb16[u][pp][128 + c]);
      float hr = bhr, hz = bhz, hn = bhn;
      #pragma unroll
      for(int q = 0; q < 8; q++){
        const uint4 hq = *(const uint4*)&hs16[u][8*q];
        hr = dot2(hq.x, wr2[4*q], hr);   hr = dot2(hq.y, wr2[4*q+1], hr);
        hr = dot2(hq.z, wr2[4*q+2], hr); hr = dot2(hq.w, wr2[4*q+3], hr);
        hz = dot2(hq.x, wz2[4*q], hz);   hz = dot2(hq.y, wz2[4*q+1], hz);
        hz = dot2(hq.z, wz2[4*q+2], hz); hz = dot2(hq.w, wz2[4*q+3], hz);
        hn = dot2(hq.x, wn2[4*q], hn);   hn = dot2(hq.y, wn2[4*q+1], hn);
        hn = dot2(hq.z, wn2[4*q+2], hn); hn = dot2(hq.w, wn2[4*q+3], hn);
      }
      const float rg = 1.f/(1.f + expf(-(xr + hr)));
      const float zg = 1.f/(1.f + expf(-(xz + hz)));
      const float ng = tanhf(xn + rg*hn);
      const float hnew = (1.f - zg)*ng + zg*hprev;
      const u16 hbits = f2h(hnew);
      hs16[u][c] = hbits; hprev = hnew;
      hist16[u][T*16 + pp][c] = hbits;
    }
  }
  if(!dir) hT[(size_t)s*NR + c] = hprev;

  // ---- epilogue: projections; lane c owns proc step p = c ----
  const int t = dir ? (NT - 1 - c) : c;
  if(!dir){
    float ap[NNE] = {pb[0], pb[1], pb[2], pb[3]};
    float ae[NNE] = {0.f, 0.f, 0.f, 0.f};
    for(int kk = 0; kk < 32; kk++){
      u32 hp; __builtin_memcpy(&hp, &hist16[u][c][2*kk], 4);
      const float h0 = h2f((u16)hp), h1 = h2f((u16)(hp >> 16));
      #pragma unroll
      for(int l = 0; l < NNE; l++){
        ap[l] += h0*pw[(2*kk)*NNE + l] + h1*pw[(2*kk+1)*NNE + l];
        ae[l] += h0*ew[(2*kk)*NNE + l] + h1*ew[(2*kk+1)*NNE + l];
      }
    }
    float4 pv = {ap[0], ap[1], ap[2], ap[3]};
    *(float4*)&outP[(((size_t)(sb*NT + t))*NEDGE + se)*NNE] = pv;
    bf16* ed = &encpF[((size_t)s*NT + t)*NNE];
    ed[0] = __float2bfloat16(ae[0]); ed[1] = __float2bfloat16(ae[1]);
    ed[2] = __float2bfloat16(ae[2]); ed[3] = __float2bfloat16(ae[3]);
  } else {
    float ae[NNE] = {0.f, 0.f, 0.f, 0.f};
    for(int kk = 0; kk < 32; kk++){
      u32 hp; __builtin_memcpy(&hp, &hist16[u][c][2*kk], 4);
      const float h0 = h2f((u16)hp), h1 = h2f((u16)(hp >> 16));
      #pragma unroll
      for(int l = 0; l < NNE; l++){
        ae[l] += h0*ew[(NR + 2*kk)*NNE + l] + h1*ew[(NR + 2*kk+1)*NNE + l];
      }
    }
    bf16* ed = &encpR[((size_t)s*NT + t)*NNE];
    ed[0] = __float2bfloat16(ae[0]); ed[1] = __float2bfloat16(ae[1]);
    ed[2] = __float2bfloat16(ae[2]); ed[3] = __float2bfloat16(ae[3]);
  }
}

// ---------------- merge enc halves + bias ----------------
__global__ void k_add(const bf16* eF, const bf16* eR, const float* eb, float* outE){
  const int i = blockIdx.x*256 + threadIdx.x;
  if(i >= PRIOR_SZ) return;
  const int l = i & 3; const int r2 = i >> 2;
  const int e = r2 % NEDGE; const int r3 = r2 / NEDGE;
  const int t = r3 % NT; const int b = r3 / NT;
  const int s = b*NEDGE + e;
  const size_t src = ((size_t)s*NT + t)*NNE + l;
  outE[i] = b2f(eF[src]) + b2f(eR[src]) + eb[l];
}

extern "C" void kernel_launch(void* const* d_in, const int* in_sizes, int n_in,
                              void* d_out, int out_size, void* d_ws, size_t ws_size,
                              hipStream_t stream)
{
  const size_t NEED = 78659584ull;
  if(ws_size < NEED){
    k_fill<<<(out_size + 255)/256, 256, 0, stream>>>((float*)d_out, out_size, 3584.0f);
    return;
  }
  const float* inp  = (const float*)d_in[0];
  const float* m1w1 = (const float*)d_in[1];  const float* m1b1 = (const float*)d_in[2];
  const float* m1w2 = (const float*)d_in[3];  const float* m1b2 = (const float*)d_in[4];
  const float* m1g  = (const float*)d_in[5];  const float* m1be = (const float*)d_in[6];
  const float* m2w1 = (const float*)d_in[7];  const float* m2b1 = (const float*)d_in[8];
  const float* m2w2 = (const float*)d_in[9];  const float* m2b2 = (const float*)d_in[10];
  const float* m2g  = (const float*)d_in[11]; const float* m2be = (const float*)d_in[12];
  const float* m3w1 = (const float*)d_in[13]; const float* m3b1 = (const float*)d_in[14];
  const float* m3w2 = (const float*)d_in[15]; const float* m3b2 = (const float*)d_in[16];
  const float* m3g  = (const float*)d_in[17]; const float* m3be = (const float*)d_in[18];
  const float* m4w1 = (const float*)d_in[19]; const float* m4b1 = (const float*)d_in[20];
  const float* m4w2 = (const float*)d_in[21]; const float* m4b2 = (const float*)d_in[22];
  const float* m4g  = (const float*)d_in[23]; const float* m4be = (const float*)d_in[24];
  const float* wihF = (const float*)d_in[25]; const float* whhF = (const float*)d_in[26];
  const float* bihF = (const float*)d_in[27]; const float* bhhF = (const float*)d_in[28];
  const float* wihR = (const float*)d_in[29]; const float* whhR = (const float*)d_in[30];
  const float* bihR = (const float*)d_in[31]; const float* bhhR = (const float*)d_in[32];
  const float* pw   = (const float*)d_in[33]; const float* pb   = (const float*)d_in[34];
  const float* ew   = (const float*)d_in[35]; const float* eb   = (const float*)d_in[36];

  char* ws = (char*)d_ws;
  float* AUX = (float*)(ws + 0);             // 16 KB reserved
  char*  Xr  = ws + 16384;                   // 6,291,456 B (X1 then X3)
  float* X   = (float*)Xr;
  bf16*  E   = (bf16*)(ws + 16384 + 6291456); // 72,351,744 B (E2 then in-place E4)
  // aliases inside X region, valid AFTER mlp4 has consumed X3:
  u32*  wihPF = (u32*)(Xr + 0);              // 49,152 B
  u32*  wihPR = (u32*)(Xr + 49152);          // 49,152 B -> 98,304
  u32*  whhPF = (u32*)(Xr + 98304);          // 24,576 B -> 122,880
  u32*  whhPR = (u32*)(Xr + 122880);         // 24,576 B -> 147,456
  bf16* encpF = (bf16*)(Xr + 147456);        // 2,260,992 B -> 2,408,448
  bf16* encpR = (bf16*)(Xr + 2408448);       // 2,260,992 B -> 4,669,440 <= 6,291,456

  float* SUM0 = AUX + 0*128;        float* SUM1 = AUX + 1*128;
  float* SUM2 = AUX + 2*128;        float* SUM3 = AUX + 3*128;
  float* SQ0  = AUX + 512 + 0*128;  float* SQ1  = AUX + 512 + 1*128;
  float* SQ2  = AUX + 512 + 2*128;  float* SQ3  = AUX + 512 + 3*128;
  float* SC0  = AUX + 1024 + 0*128; float* SC1  = AUX + 1024 + 1*128;
  float* SC2  = AUX + 1024 + 2*128; float* SC3  = AUX + 1024 + 3*128;
  float* SH0  = AUX + 1536 + 0*128; float* SH1  = AUX + 1536 + 1*128;
  float* SH2  = AUX + 1536 + 2*128; float* SH3  = AUX + 1536 + 3*128;

  float* outP = (float*)d_out;
  float* outE = outP + PRIOR_SZ;
  float* hT   = outP + 2*PRIOR_SZ;

  k_zero<<<1, 256, 0, stream>>>(AUX);
  k_mlp1<<<ROWS1/16, 128, 0, stream>>>(inp, m1w1, m1b1, m1w2, m1b2, X, SUM0, SQ0);
  k_bn<<<1, 128, 0, stream>>>(SUM0, SQ0, m1g, m1be, 1.f/ROWS1, SC0, SH0);
  k_mlp_edge<2*NH><<<ROWS2/16, 128, 0, stream>>>(X, SC0, SH0, nullptr, nullptr, nullptr,
                                                 m2w1, m2b1, m2w2, m2b2, E, SUM1, SQ1);
  k_bn<<<1, 128, 0, stream>>>(SUM1, SQ1, m2g, m2be, 1.f/ROWS2, SC1, SH1);
  k_mlp3<<<ROWS1/16, 128, 0, stream>>>(E, SC1, SH1, m3w1, m3b1, m3w2, m3b2, X, SUM2, SQ2);
  k_bn<<<1, 128, 0, stream>>>(SUM2, SQ2, m3g, m3be, 1.f/ROWS1, SC2, SH2);
  k_mlp_edge<3*NH><<<ROWS2/16, 128, 0, stream>>>(X, SC2, SH2, E, SC1, SH1,
                                                 m4w1, m4b1, m4w2, m4b2, E, SUM3, SQ3);
  k_bn<<<1, 128, 0, stream>>>(SUM3, SQ3, m4g, m4be, 1.f/ROWS2, SC3, SH3);
  // X region is now dead -> pack GRU weights into it (f16 pairs)
  k_prep<<<48, 256, 0, stream>>>(wihF, whhF, wihR, whhR, wihPF, whhPF, wihPR, whhPR);
  k_gru<<<NSEQ, 128, 0, stream>>>(E, SC3, SH3,
                                  wihPF, whhPF, bihF, bhhF,
                                  wihPR, whhPR, bihR, bhhR,
                                  pw, pb, ew, encpF, encpR, outP, hT);
  k_add<<<(PRIOR_SZ + 255)/256, 256, 0, stream>>>(encpF, encpR, eb, outE);
}

// Round 12
// 1870.725 us; speedup vs baseline: 3.0887x; 1.0803x over previous
//
#include <hip/hip_runtime.h>
#include <hip/hip_bf16.h>
#include <cstring>

// ---- problem constants ----
#define NB 8
#define NT 64
#define NNODE 24
#define ND 6
#define NH 128
#define NR 64
#define NNE 4
#define NEDGE 552                  // NNODE*(NNODE-1)
#define NSEQ (NB*NEDGE)            // 4416
#define ROWS1 (NB*NNODE*NT)        // 12288
#define ROWS2 (NB*NEDGE*NT)        // 282624
#define PRIOR_SZ (NB*NT*NEDGE*NNE) // 1130496

typedef __hip_bfloat16 bf16;
typedef unsigned short u16;
typedef unsigned int u32;
typedef _Float16 f16;
typedef __attribute__((ext_vector_type(2))) _Float16 f16x2;

__device__ __forceinline__ float eluf(float x){ return x > 0.f ? x : expm1f(x); }
__device__ __forceinline__ float b2f(bf16 v){ return __bfloat162float(v); }
__device__ __forceinline__ u16 f2h(float x){ f16 h = (f16)x; u16 v; __builtin_memcpy(&v, &h, 2); return v; }
__device__ __forceinline__ float h2f(u16 v){ f16 h; __builtin_memcpy(&h, &v, 2); return (float)h; }
__device__ __forceinline__ u32 packf2(float a, float b){ return (u32)f2h(a) | ((u32)f2h(b) << 16); }

#if defined(__has_builtin)
#if __has_builtin(__builtin_amdgcn_fdot2)
#define HAS_DOT2 1
#endif
#endif

#ifdef HAS_DOT2
__device__ __forceinline__ float dot2(u32 a, u32 b, float c){
  f16x2 av, bv;
  __builtin_memcpy(&av, &a, 4); __builtin_memcpy(&bv, &b, 4);
  return __builtin_amdgcn_fdot2(av, bv, c, false);
}
#else
__device__ __forceinline__ float dot2(u32 a, u32 b, float c){
  return c + h2f((u16)a)*h2f((u16)b) + h2f((u16)(a>>16))*h2f((u16)(b>>16));
}
#endif

// ---------------- diagnostics / setup ----------------
__global__ void k_fill(float* out, int n, float pat){
  const int i = blockIdx.x*256 + threadIdx.x;
  if(i < n) out[i] = pat;
}
__global__ void k_zero(float* aux){
  for(int i = threadIdx.x; i < 1024; i += 256) aux[i] = 0.f;
}

// pack MLP2/MLP4 weights as k-pair f16x2: wP[k2*NH + j] = (w[2k2][j], w[2k2+1][j])
__global__ void k_prep_mlp(const float* w2a, const float* w2b,
                           const float* w4a, const float* w4b,
                           u32* w2aP, u32* w2bP, u32* w4aP, u32* w4bP)
{
  const int i = blockIdx.x*256 + threadIdx.x;
  const int k2 = i >> 7, j = i & 127;
  if(i < 128*128)
    w2aP[k2*NH + j] = packf2(w2a[(2*k2)*NH + j], w2a[(2*k2+1)*NH + j]);
  if(i < 64*128){
    w2bP[k2*NH + j] = packf2(w2b[(2*k2)*NH + j], w2b[(2*k2+1)*NH + j]);
    w4bP[k2*NH + j] = packf2(w4b[(2*k2)*NH + j], w4b[(2*k2+1)*NH + j]);
  }
  if(i < 192*128)
    w4aP[k2*NH + j] = packf2(w4a[(2*k2)*NH + j], w4a[(2*k2+1)*NH + j]);
}

// pack GRU weights as pair-transposed f16x2 (runs after MLP4; X region dead)
__global__ void k_prep(const float* wihF, const float* whhF,
                       const float* wihR, const float* whhR,
                       u32* wihPF, u32* whhPF, u32* wihPR, u32* whhPR)
{
  const int i = blockIdx.x*256 + threadIdx.x;
  if(i < 192*64){
    const int r = i >> 6, k2 = i & 63;
    wihPF[k2*192 + r] = packf2(wihF[r*NH + 2*k2], wihF[r*NH + 2*k2 + 1]);
    wihPR[k2*192 + r] = packf2(wihR[r*NH + 2*k2], wihR[r*NH + 2*k2 + 1]);
  }
  if(i < 192*32){
    const int r = i >> 5, k2 = i & 31;
    whhPF[k2*192 + r] = packf2(whhF[r*NR + 2*k2], whhF[r*NR + 2*k2 + 1]);
    whhPR[k2*192 + r] = packf2(whhR[r*NR + 2*k2], whhR[r*NR + 2*k2 + 1]);
  }
}

// ---------------- MLP1: (B,N,T,D)->H->H, pre-BN out + channel sums -------------
__global__ __launch_bounds__(128) void k_mlp1(
    const float* inp, const float* w1, const float* b1,
    const float* w2, const float* b2,
    float* X1, float* sum, float* sq)
{
  const int j = threadIdx.x;
  __shared__ float xin[ND];
  __shared__ float h1[NH];
  const float b1j = b1[j], b2j = b2[j];
  float wcol[ND];
  for(int d = 0; d < ND; d++) wcol[d] = w1[d*NH + j];
  float accS = 0.f, accQ = 0.f;
  const int row0 = blockIdx.x*16;
  for(int r = 0; r < 16; r++){
    const int row = row0 + r;
    const int b = row/(NNODE*NT); const int rem = row - b*(NNODE*NT);
    const int n = rem/NT; const int t = rem - n*NT;
    if(j < ND) xin[j] = inp[((b*NT + t)*NNODE + n)*ND + j];
    __syncthreads();
    float a = b1j;
    for(int d = 0; d < ND; d++) a += xin[d]*wcol[d];
    h1[j] = eluf(a);
    __syncthreads();
    float a2 = b2j;
    for(int k = 0; k < NH; k++) a2 += h1[k]*w2[k*NH + j];
    const float h2 = eluf(a2);
    X1[row*NH + j] = h2; accS += h2; accQ += h2*h2;
    __syncthreads();
  }
  atomicAdd(&sum[j], accS); atomicAdd(&sq[j], accQ);
}

// ---------------- BN params ----------------
__global__ void k_bn(const float* sum, const float* sq,
                     const float* g, const float* be,
                     float inv_cnt, float* sc, float* sh)
{
  const int j = threadIdx.x;
  const float m = sum[j]*inv_cnt;
  const float v = fmaxf(sq[j]*inv_cnt - m*m, 0.f);
  const float s = g[j]*rsqrtf(v + 1e-5f);
  sc[j] = s; sh[j] = be[j] - m*s;
}

// ---------------- edge MLPs (MLP2: KIN=256, MLP4: KIN=384), CH=16, f16 dot2 ----
// Staging in natural [row][k] f16 layout (conflict-free 2-lanes/bank-word).
// Inner loops: 4 coalesced weight-pair loads + per-row uint4 broadcast LDS read
// + 4 dot2 (8 MACs). For KIN=384 Eo may alias Ein (in-place): block stages its
// own 16 rows before overwriting them.
template<int KIN>
__global__ __launch_bounds__(128) void k_mlp_edge(
  const float* Xn, const float* scN, const float* shN,
  const bf16* Ein, const float* scE, const float* shE,
  const u32* w1P, const float* b1, const u32* w2P, const float* b2,
  bf16* Eo, float* sum, float* sq)
{
  const int j = threadIdx.x;
  constexpr int CH = 16;
  __shared__ __align__(16) u16 xin16[CH][KIN];
  __shared__ __align__(16) u16 h1s16[CH][NH];
  const int g0 = blockIdx.x*CH;
  const int b = g0/(NEDGE*NT); const int rem = g0 - b*(NEDGE*NT);
  const int e = rem/NT; const int t0 = rem - e*NT;
  const int snd = e/23, r0 = e - snd*23;
  const int rcv = r0 + (r0 >= snd ? 1 : 0);
  const float sN = scN[j], tN = shN[j];
  float sE = 0.f, tE = 0.f;
  if constexpr(KIN == 3*NH){ sE = scE[j]; tE = shE[j]; }
  const int baseS = ((b*NNODE + snd)*NT + t0)*NH;
  const int baseR = ((b*NNODE + rcv)*NT + t0)*NH;
  for(int r = 0; r < CH; r++){
    xin16[r][j]      = f2h(Xn[baseS + r*NH + j]*sN + tN);
    xin16[r][NH + j] = f2h(Xn[baseR + r*NH + j]*sN + tN);
    if constexpr(KIN == 3*NH)
      xin16[r][2*NH + j] = f2h(b2f(Ein[(size_t)(g0 + r)*NH + j])*sE + tE);
  }
  __syncthreads();
  float acc[CH];
  const float b1j = b1[j];
  #pragma unroll
  for(int r = 0; r < CH; r++) acc[r] = b1j;
  for(int kb = 0; kb < KIN/8; kb++){
    u32 w[4];
    #pragma unroll
    for(int q = 0; q < 4; q++) w[q] = w1P[(size_t)(4*kb + q)*NH + j];
    #pragma unroll
    for(int r = 0; r < CH; r++){
      const uint4 xq = *(const uint4*)&xin16[r][8*kb];
      acc[r] = dot2(xq.x, w[0], acc[r]);
      acc[r] = dot2(xq.y, w[1], acc[r]);
      acc[r] = dot2(xq.z, w[2], acc[r]);
      acc[r] = dot2(xq.w, w[3], acc[r]);
    }
  }
  #pragma unroll
  for(int r = 0; r < CH; r++) h1s16[r][j] = f2h(eluf(acc[r]));
  __syncthreads();
  const float b2j = b2[j];
  #pragma unroll
  for(int r = 0; r < CH; r++) acc[r] = b2j;
  for(int kb = 0; kb < NH/8; kb++){
    u32 w[4];
    #pragma unroll
    for(int q = 0; q < 4; q++) w[q] = w2P[(size_t)(4*kb + q)*NH + j];
    #pragma unroll
    for(int r = 0; r < CH; r++){
      const uint4 hq = *(const uint4*)&h1s16[r][8*kb];
      acc[r] = dot2(hq.x, w[0], acc[r]);
      acc[r] = dot2(hq.y, w[1], acc[r]);
      acc[r] = dot2(hq.z, w[2], acc[r]);
      acc[r] = dot2(hq.w, w[3], acc[r]);
    }
  }
  float accS = 0.f, accQ = 0.f;
  #pragma unroll
  for(int r = 0; r < CH; r++){
    const float h2 = eluf(acc[r]);
    Eo[(size_t)(g0 + r)*NH + j] = __float2bfloat16(h2);
    accS += h2; accQ += h2*h2;
  }
  atomicAdd(&sum[j], accS); atomicAdd(&sq[j], accQ);
}

// ---------------- agg (mean over incoming edges) + MLP3 ----------------
__global__ __launch_bounds__(128) void k_mlp3(
    const bf16* Ein, const float* scE, const float* shE,
    const float* w1, const float* b1, const float* w2, const float* b2,
    float* X3, float* sum, float* sq)
{
  const int j = threadIdx.x;
  __shared__ float xin[NH];
  __shared__ float h1[NH];
  const float sE = scE[j], tE = shE[j];
  float accS = 0.f, accQ = 0.f;
  const int row0 = blockIdx.x*16;
  for(int r = 0; r < 16; r++){
    const int row = row0 + r;
    const int b = row/(NNODE*NT); const int rem = row - b*(NNODE*NT);
    const int n = rem/NT; const int t = rem - n*NT;
    float s = 0.f;
    for(int i = 0; i < NNODE; i++){
      if(i == n) continue;
      const int e = i*23 + (n < i ? n : n - 1);
      s += b2f(Ein[((size_t)(b*NEDGE + e)*NT + t)*NH + j]);
    }
    xin[j] = sE*s*(1.f/23.f) + tE;
    __syncthreads();
    float a = b1[j];
    for(int k = 0; k < NH; k++) a += xin[k]*w1[k*NH + j];
    h1[j] = eluf(a);
    __syncthreads();
    float a2 = b2[j];
    for(int k = 0; k < NH; k++) a2 += h1[k]*w2[k*NH + j];
    const float h2 = eluf(a2);
    X3[row*NH + j] = h2; accS += h2; accQ += h2*h2;
    __syncthreads();
  }
  atomicAdd(&sum[j], accS); atomicAdd(&sq[j], accQ);
}

// ---------------- GRU: 2 independent (seq,dir) units per 128-thread block -----
// f16 data path with v_dot2_f32_f16. Wave-private LDS => NO barriers.
__global__ __launch_bounds__(128) void k_gru(
  const bf16* E4, const float* sc4, const float* sh4,
  const u32* wihPF, const u32* whhPF, const float* bihF, const float* bhhF,
  const u32* wihPR, const u32* whhPR, const float* bihR, const float* bhhR,
  const float* pw, const float* pb, const float* ew,
  bf16* encpF, bf16* encpR, float* outP, float* hT)
{
  __shared__ __align__(16) u16 xst16[2][16][NH];   // 8192 B
  __shared__ __align__(16) u16 xwb16[2][16][192];  // 12288 B
  __shared__ __align__(16) u16 hist16[2][NT][66];  // 16896 B
  __shared__ __align__(16) u16 hs16[2][NR];        // 256 B
  const int tid = threadIdx.x;
  const int u = tid >> 6, c = tid & 63;
  const int gid = blockIdx.x*2 + u;
  const int dir = (gid >= NSEQ) ? 1 : 0;
  const int s = dir ? (gid - NSEQ) : gid;
  const int sb = s / NEDGE, se = s - sb*NEDGE;
  const u32* wihP = dir ? wihPR : wihPF;
  const u32* whhP = dir ? whhPR : whhPF;
  const float* bih = dir ? bihR : bihF;
  const float* bhh = dir ? bhhR : bhhF;
  const float bxr = bih[c], bxz = bih[64+c], bxn = bih[128+c];
  const float bhr = bhh[c], bhz = bhh[64+c], bhn = bhh[128+c];
  const float sc_a = sc4[c], sc_b = sc4[c+64];
  const float sh_a = sh4[c], sh_b = sh4[c+64];

  u32 wr2[32], wz2[32], wn2[32];
  #pragma unroll
  for(int kk = 0; kk < 32; kk++){
    wr2[kk] = whhP[kk*192 + c];
    wz2[kk] = whhP[kk*192 + 64 + c];
    wn2[kk] = whhP[kk*192 + 128 + c];
  }

  hs16[u][c] = 0;
  float hprev = 0.f;

  for(int T = 0; T < 4; T++){
    for(int tp = 0; tp < 16; tp++){
      const int p = T*16 + tp;
      const int t = dir ? (NT - 1 - p) : p;
      const size_t xb = ((size_t)s*NT + t)*NH;
      xst16[u][tp][c]      = f2h(b2f(E4[xb + c])*sc_a + sh_a);
      xst16[u][tp][c + 64] = f2h(b2f(E4[xb + c + 64])*sc_b + sh_b);
    }
    float ar[16], az[16], an[16];
    #pragma unroll
    for(int tp = 0; tp < 16; tp++){ ar[tp] = bxr; az[tp] = bxz; an[tp] = bxn; }
    for(int kb = 0; kb < 16; kb++){
      u32 wr[4], wz[4], wn[4];
      #pragma unroll
      for(int j = 0; j < 4; j++){
        const u32* wp = wihP + (size_t)(4*kb + j)*192;
        wr[j] = wp[c]; wz[j] = wp[64 + c]; wn[j] = wp[128 + c];
      }
      #pragma unroll
      for(int tp = 0; tp < 16; tp++){
        const uint4 xq = *(const uint4*)&xst16[u][tp][8*kb];
        ar[tp] = dot2(xq.x, wr[0], ar[tp]); ar[tp] = dot2(xq.y, wr[1], ar[tp]);
        ar[tp] = dot2(xq.z, wr[2], ar[tp]); ar[tp] = dot2(xq.w, wr[3], ar[tp]);
        az[tp] = dot2(xq.x, wz[0], az[tp]); az[tp] = dot2(xq.y, wz[1], az[tp]);
        az[tp] = dot2(xq.z, wz[2], az[tp]); az[tp] = dot2(xq.w, wz[3], az[tp]);
        an[tp] = dot2(xq.x, wn[0], an[tp]); an[tp] = dot2(xq.y, wn[1], an[tp]);
        an[tp] = dot2(xq.z, wn[2], an[tp]); an[tp] = dot2(xq.w, wn[3], an[tp]);
      }
    }
    #pragma unroll
    for(int tp = 0; tp < 16; tp++){
      xwb16[u][tp][c]       = f2h(ar[tp]);
      xwb16[u][tp][64 + c]  = f2h(az[tp]);
      xwb16[u][tp][128 + c] = f2h(an[tp]);
    }
    for(int pp = 0; pp < 16; pp++){
      const float xr = h2f(xwb16[u][pp][c]);
      const float xz = h2f(xwb16[u][pp][64 + c]);
      const float xn = h2f(xwb16[u][pp][128 + c]);
      float hr = bhr, hz = bhz, hn = bhn;
      #pragma unroll
      for(int q = 0; q < 8; q++){
        const uint4 hq = *(const uint4*)&hs16[u][8*q];
        hr = dot2(hq.x, wr2[4*q], hr);   hr = dot2(hq.y, wr2[4*q+1], hr);
        hr = dot2(hq.z, wr2[4*q+2], hr); hr = dot2(hq.w, wr2[4*q+3], hr);
        hz = dot2(hq.x, wz2[4*q], hz);   hz = dot2(hq.y, wz2[4*q+1], hz);
        hz = dot2(hq.z, wz2[4*q+2], hz); hz = dot2(hq.w, wz2[4*q+3], hz);
        hn = dot2(hq.x, wn2[4*q], hn);   hn = dot2(hq.y, wn2[4*q+1], hn);
        hn = dot2(hq.z, wn2[4*q+2], hn); hn = dot2(hq.w, wn2[4*q+3], hn);
      }
      const float rg = 1.f/(1.f + expf(-(xr + hr)));
      const float zg = 1.f/(1.f + expf(-(xz + hz)));
      const float ng = tanhf(xn + rg*hn);
      const float hnew = (1.f - zg)*ng + zg*hprev;
      const u16 hbits = f2h(hnew);
      hs16[u][c] = hbits; hprev = hnew;
      hist16[u][T*16 + pp][c] = hbits;
    }
  }
  if(!dir) hT[(size_t)s*NR + c] = hprev;

  const int t = dir ? (NT - 1 - c) : c;
  if(!dir){
    float ap[NNE] = {pb[0], pb[1], pb[2], pb[3]};
    float ae[NNE] = {0.f, 0.f, 0.f, 0.f};
    for(int kk = 0; kk < 32; kk++){
      u32 hp; __builtin_memcpy(&hp, &hist16[u][c][2*kk], 4);
      const float h0 = h2f((u16)hp), h1 = h2f((u16)(hp >> 16));
      #pragma unroll
      for(int l = 0; l < NNE; l++){
        ap[l] += h0*pw[(2*kk)*NNE + l] + h1*pw[(2*kk+1)*NNE + l];
        ae[l] += h0*ew[(2*kk)*NNE + l] + h1*ew[(2*kk+1)*NNE + l];
      }
    }
    float4 pv = {ap[0], ap[1], ap[2], ap[3]};
    *(float4*)&outP[(((size_t)(sb*NT + t))*NEDGE + se)*NNE] = pv;
    bf16* ed = &encpF[((size_t)s*NT + t)*NNE];
    ed[0] = __float2bfloat16(ae[0]); ed[1] = __float2bfloat16(ae[1]);
    ed[2] = __float2bfloat16(ae[2]); ed[3] = __float2bfloat16(ae[3]);
  } else {
    float ae[NNE] = {0.f, 0.f, 0.f, 0.f};
    for(int kk = 0; kk < 32; kk++){
      u32 hp; __builtin_memcpy(&hp, &hist16[u][c][2*kk], 4);
      const float h0 = h2f((u16)hp), h1 = h2f((u16)(hp >> 16));
      #pragma unroll
      for(int l = 0; l < NNE; l++){
        ae[l] += h0*ew[(NR + 2*kk)*NNE + l] + h1*ew[(NR + 2*kk+1)*NNE + l];
      }
    }
    bf16* ed = &encpR[((size_t)s*NT + t)*NNE];
    ed[0] = __float2bfloat16(ae[0]); ed[1] = __float2bfloat16(ae[1]);
    ed[2] = __float2bfloat16(ae[2]); ed[3] = __float2bfloat16(ae[3]);
  }
}

// ---------------- merge enc halves + bias ----------------
__global__ void k_add(const bf16* eF, const bf16* eR, const float* eb, float* outE){
  const int i = blockIdx.x*256 + threadIdx.x;
  if(i >= PRIOR_SZ) return;
  const int l = i & 3; const int r2 = i >> 2;
  const int e = r2 % NEDGE; const int r3 = r2 / NEDGE;
  const int t = r3 % NT; const int b = r3 / NT;
  const int s = b*NEDGE + e;
  const size_t src = ((size_t)s*NT + t)*NNE + l;
  outE[i] = b2f(eF[src]) + b2f(eR[src]) + eb[l];
}

extern "C" void kernel_launch(void* const* d_in, const int* in_sizes, int n_in,
                              void* d_out, int out_size, void* d_ws, size_t ws_size,
                              hipStream_t stream)
{
  const size_t NEED = 78888960ull;   // +229 KB WPACK after E; known ws >= 83,181,568
  if(ws_size < NEED){
    k_fill<<<(out_size + 255)/256, 256, 0, stream>>>((float*)d_out, out_size, 3584.0f);
    return;
  }
  const float* inp  = (const float*)d_in[0];
  const float* m1w1 = (const float*)d_in[1];  const float* m1b1 = (const float*)d_in[2];
  const float* m1w2 = (const float*)d_in[3];  const float* m1b2 = (const float*)d_in[4];
  const float* m1g  = (const float*)d_in[5];  const float* m1be = (const float*)d_in[6];
  const float* m2w1 = (const float*)d_in[7];  const float* m2b1 = (const float*)d_in[8];
  const float* m2w2 = (const float*)d_in[9];  const float* m2b2 = (const float*)d_in[10];
  const float* m2g  = (const float*)d_in[11]; const float* m2be = (const float*)d_in[12];
  const float* m3w1 = (const float*)d_in[13]; const float* m3b1 = (const float*)d_in[14];
  const float* m3w2 = (const float*)d_in[15]; const float* m3b2 = (const float*)d_in[16];
  const float* m3g  = (const float*)d_in[17]; const float* m3be = (const float*)d_in[18];
  const float* m4w1 = (const float*)d_in[19]; const float* m4b1 = (const float*)d_in[20];
  const float* m4w2 = (const float*)d_in[21]; const float* m4b2 = (const float*)d_in[22];
  const float* m4g  = (const float*)d_in[23]; const float* m4be = (const float*)d_in[24];
  const float* wihF = (const float*)d_in[25]; const float* whhF = (const float*)d_in[26];
  const float* bihF = (const float*)d_in[27]; const float* bhhF = (const float*)d_in[28];
  const float* wihR = (const float*)d_in[29]; const float* whhR = (const float*)d_in[30];
  const float* bihR = (const float*)d_in[31]; const float* bhhR = (const float*)d_in[32];
  const float* pw   = (const float*)d_in[33]; const float* pb   = (const float*)d_in[34];
  const float* ew   = (const float*)d_in[35]; const float* eb   = (const float*)d_in[36];

  char* ws = (char*)d_ws;
  float* AUX = (float*)(ws + 0);             // 16 KB reserved
  char*  Xr  = ws + 16384;                   // 6,291,456 B (X1 then X3)
  float* X   = (float*)Xr;
  bf16*  E   = (bf16*)(ws + 16384 + 6291456); // 72,351,744 B (E2 then in-place E4)
  char*  WP  = ws + 78659584;                // 229,376 B MLP weight packs
  u32* w2aP = (u32*)(WP + 0);                // 65,536 B (128 pairs x 128)
  u32* w2bP = (u32*)(WP + 65536);            // 32,768 B (64 pairs x 128)
  u32* w4aP = (u32*)(WP + 98304);            // 98,304 B (192 pairs x 128)
  u32* w4bP = (u32*)(WP + 196608);           // 32,768 B
  // aliases inside X region, valid AFTER mlp4 has consumed X3:
  u32*  wihPF = (u32*)(Xr + 0);              // 49,152 B
  u32*  wihPR = (u32*)(Xr + 49152);          // 49,152 B -> 98,304
  u32*  whhPF = (u32*)(Xr + 98304);          // 24,576 B -> 122,880
  u32*  whhPR = (u32*)(Xr + 122880);         // 24,576 B -> 147,456
  bf16* encpF = (bf16*)(Xr + 147456);        // 2,260,992 B -> 2,408,448
  bf16* encpR = (bf16*)(Xr + 2408448);       // 2,260,992 B -> 4,669,440 <= 6,291,456

  float* SUM0 = AUX + 0*128;        float* SUM1 = AUX + 1*128;
  float* SUM2 = AUX + 2*128;        float* SUM3 = AUX + 3*128;
  float* SQ0  = AUX + 512 + 0*128;  float* SQ1  = AUX + 512 + 1*128;
  float* SQ2  = AUX + 512 + 2*128;  float* SQ3  = AUX + 512 + 3*128;
  float* SC0  = AUX + 1024 + 0*128; float* SC1  = AUX + 1024 + 1*128;
  float* SC2  = AUX + 1024 + 2*128; float* SC3  = AUX + 1024 + 3*128;
  float* SH0  = AUX + 1536 + 0*128; float* SH1  = AUX + 1536 + 1*128;
  float* SH2  = AUX + 1536 + 2*128; float* SH3  = AUX + 1536 + 3*128;

  float* outP = (float*)d_out;
  float* outE = outP + PRIOR_SZ;
  float* hT   = outP + 2*PRIOR_SZ;

  k_zero<<<1, 256, 0, stream>>>(AUX);
  k_prep_mlp<<<96, 256, 0, stream>>>(m2w1, m2w2, m4w1, m4w2, w2aP, w2bP, w4aP, w4bP);
  k_mlp1<<<ROWS1/16, 128, 0, stream>>>(inp, m1w1, m1b1, m1w2, m1b2, X, SUM0, SQ0);
  k_bn<<<1, 128, 0, stream>>>(SUM0, SQ0, m1g, m1be, 1.f/ROWS1, SC0, SH0);
  k_mlp_edge<2*NH><<<ROWS2/16, 128, 0, stream>>>(X, SC0, SH0, nullptr, nullptr, nullptr,
                                                 w2aP, m2b1, w2bP, m2b2, E, SUM1, SQ1);
  k_bn<<<1, 128, 0, stream>>>(SUM1, SQ1, m2g, m2be, 1.f/ROWS2, SC1, SH1);
  k_mlp3<<<ROWS1/16, 128, 0, stream>>>(E, SC1, SH1, m3w1, m3b1, m3w2, m3b2, X, SUM2, SQ2);
  k_bn<<<1, 128, 0, stream>>>(SUM2, SQ2, m3g, m3be, 1.f/ROWS1, SC2, SH2);
  k_mlp_edge<3*NH><<<ROWS2/16, 128, 0, stream>>>(X, SC2, SH2, E, SC1, SH1,
                                                 w4aP, m4b1, w4bP, m4b2, E, SUM3, SQ3);
  k_bn<<<1, 128, 0, stream>>>(SUM3, SQ3, m4g, m4be, 1.f/ROWS2, SC3, SH3);
  // X region is now dead -> pack GRU weights into it (f16 pairs)
  k_prep<<<48, 256, 0, stream>>>(wihF, whhF, wihR, whhR, wihPF, whhPF, wihPR, whhPR);
  k_gru<<<NSEQ, 128, 0, stream>>>(E, SC3, SH3,
                                  wihPF, whhPF, bihF, bhhF,
                                  wihPR, whhPR, bihR, bhhR,
                                  pw, pb, ew, encpF, encpR, outP, hT);
  k_add<<<(PRIOR_SZ + 255)/256, 256, 0, stream>>>(encpF, encpR, eb, outE);
}